// Round 4
// baseline (472.727 us; speedup 1.0000x reference)
//
#include <hip/hip_runtime.h>
#include <hip/hip_bf16.h>

typedef unsigned long long u64;
typedef unsigned int u32;

#define NTOT    54560   // anchors per batch (r + i)
#define NMOD    27280   // anchors per modality
#define BATCH   16
#define KPAD    1024
#define MAXD    1000
#define NBIN    16384   // score-bits >> 16 (score <= 1.0 -> bin <= 0x3F80)
#define CANDCAP 6144

struct Ptrs { const float* p[30]; };

// ---------------- workspace layout (16B aligned) ----------------
constexpr size_t SZ_KEY   = (size_t)BATCH * NTOT * 8;        // 7 MB
constexpr size_t SZ_TOPK  = (size_t)BATCH * KPAD * 8;
constexpr size_t SZ_CAND  = (size_t)BATCH * CANDCAP * 8;
constexpr size_t SZ_TRAW  = (size_t)BATCH * KPAD * 16;
constexpr size_t SZ_T1    = (size_t)BATCH * KPAD * 4;
constexpr size_t SZ_SELB  = (size_t)BATCH * 4;
constexpr size_t SZ_HIST  = (size_t)BATCH * NBIN * 4;        // 1 MB
constexpr size_t SZ_MASK  = (size_t)BATCH * KPAD * 32 * 4;   // 2 MB
constexpr size_t SZ_CNT   = 64;
constexpr size_t SZ_MAXC  = 64;
constexpr size_t SZ_VAL   = (size_t)BATCH * 32 * 4;

constexpr size_t OFF_KEY    = 0;
constexpr size_t OFF_TOPK   = OFF_KEY   + SZ_KEY;
constexpr size_t OFF_CAND   = OFF_TOPK  + SZ_TOPK;
constexpr size_t OFF_TRAW   = OFF_CAND  + SZ_CAND;
constexpr size_t OFF_TSCORE = OFF_TRAW  + SZ_TRAW;
constexpr size_t OFF_TCLSF  = OFF_TSCORE+ SZ_T1;
constexpr size_t OFF_SELB   = OFF_TCLSF + SZ_T1;
// 2MB BIG region: hist (1MB) lives here early; maskG (2MB) reuses it after
// scanB1 has consumed hist.
constexpr size_t OFF_BIG    = OFF_SELB  + SZ_SELB + 192;  // keep 16B-align slack
constexpr size_t OFF_HIST   = OFF_BIG;
constexpr size_t OFF_MASK   = OFF_BIG;
constexpr size_t OFF_CNT    = OFF_BIG  + SZ_MASK;
constexpr size_t OFF_MAXC   = OFF_CNT  + SZ_CNT;
constexpr size_t OFF_VALID  = OFF_MAXC + SZ_MAXC;

__device__ inline void level_of(int nm, int& l, int& pos, int& w, int& s, int& hw) {
    if (nm < 20480)      { l = 0; pos = nm;         w = 160; s = 8;   hw = 20480; }
    else if (nm < 25600) { l = 1; pos = nm - 20480; w = 80;  s = 16;  hw = 5120; }
    else if (nm < 26880) { l = 2; pos = nm - 25600; w = 40;  s = 32;  hw = 1280; }
    else if (nm < 27200) { l = 3; pos = nm - 26880; w = 20;  s = 64;  hw = 320; }
    else                 { l = 4; pos = nm - 27200; w = 10;  s = 128; hw = 80; }
}

__device__ inline float sigm(float x) { return 1.0f / (1.0f + expf(-x)); }

// ---------------- kernel 1: decode scores -> keys + histogram ----------------
// 1 thread = 4 consecutive anchors. All 21 loads issued into a register array
// BEFORE any consumption -> single vmcnt batch (one HBM latency per thread).
__global__ __launch_bounds__(256)
void decode_kernel(Ptrs ptrs, ulonglong2* __restrict__ keyAll2, u32* __restrict__ hist) {
    int t = blockIdx.x * 256 + threadIdx.x;
    int b = blockIdx.y;
    if (t >= NTOT / 4) return;
    int n0 = t * 4;
    int mod = (n0 >= NMOD) ? 1 : 0;
    int nm = n0 - mod * NMOD;
    int l, pos, w, s, hw;
    level_of(nm, l, pos, w, s, hw);
    (void)w; (void)s;
    const float* clsP = ptrs.p[mod * 15 + l];
    const float* cntP = ptrs.p[mod * 15 + 5 + l];

    const float4* cb = (const float4*)(clsP + (size_t)b * 20 * hw + pos);
    int hw4 = hw >> 2;
    float4 v[20];
    #pragma unroll
    for (int c = 0; c < 20; ++c) v[c] = cb[(size_t)c * hw4];
    float4 cv = *(const float4*)(cntP + (size_t)b * hw + pos);

    float4 mx = v[0];
    #pragma unroll
    for (int c = 1; c < 20; ++c) {
        mx.x = fmaxf(mx.x, v[c].x); mx.y = fmaxf(mx.y, v[c].y);
        mx.z = fmaxf(mx.z, v[c].z); mx.w = fmaxf(mx.w, v[c].w);
    }

    float mxa[4] = {mx.x, mx.y, mx.z, mx.w};
    float cva[4] = {cv.x, cv.y, cv.z, cv.w};
    u32 sb[4];
    #pragma unroll
    for (int a = 0; a < 4; ++a) {
        float pb = sigm(mxa[a]);        // max-before-sigmoid: bitwise equal (monotone)
        float pc = sigm(cva[a]);
        sb[a] = __float_as_uint(sqrtf(__fmul_rn(pb, pc)));
    }
    ulonglong2 k01, k23;
    k01.x = ((u64)sb[0] << 16) | (u64)(65535 - (n0 + 0));
    k01.y = ((u64)sb[1] << 16) | (u64)(65535 - (n0 + 1));
    k23.x = ((u64)sb[2] << 16) | (u64)(65535 - (n0 + 2));
    k23.y = ((u64)sb[3] << 16) | (u64)(65535 - (n0 + 3));
    size_t o2 = ((size_t)b * NTOT + n0) >> 1;
    keyAll2[o2]     = k01;
    keyAll2[o2 + 1] = k23;

    u32* hb = hist + (size_t)b * NBIN;
    #pragma unroll
    for (int a = 0; a < 4; ++a) atomicAdd(&hb[sb[a] >> 16], 1u);
}

// ---------------- kernel 2: per-batch threshold bin B1 ----------------
__global__ __launch_bounds__(1024)
void scanB1_kernel(const u32* __restrict__ hist, int* __restrict__ selB1) {
    int b = blockIdx.x, tid = threadIdx.x;
    __shared__ u32 ps[1024];
    const u32* h = hist + (size_t)b * NBIN;
    u32 loc[16]; u32 sum = 0;
    #pragma unroll
    for (int j = 0; j < 16; ++j) { loc[j] = h[NBIN - 1 - (tid * 16 + j)]; sum += loc[j]; }
    ps[tid] = sum;
    __syncthreads();
    for (int off = 1; off < 1024; off <<= 1) {
        u32 v = (tid >= off) ? ps[tid - off] : 0u;
        __syncthreads();
        ps[tid] += v;
        __syncthreads();
    }
    u32 incl = ps[tid], excl = incl - sum;
    if (excl < (u32)MAXD && incl >= (u32)MAXD) {
        u32 c = excl;
        #pragma unroll
        for (int j = 0; j < 16; ++j) {
            c += loc[j];
            if (c >= (u32)MAXD) { selB1[b] = NBIN - 1 - (tid * 16 + j); break; }
        }
    }
}

// ---------------- kernel 3: compact keys with bin >= B1 (full grid) ----------------
__global__ __launch_bounds__(256)
void compact_kernel(const u64* __restrict__ keyAll, const int* __restrict__ selB1,
                    u32* __restrict__ cntG, u64* __restrict__ candbuf) {
    int n = blockIdx.x * 256 + threadIdx.x;
    int b = blockIdx.y;
    if (n >= NTOT) return;
    u64 k = keyAll[(size_t)b * NTOT + n];
    if ((int)(k >> 32) >= selB1[b]) {
        u32 p = atomicAdd(&cntG[b], 1u);
        if (p < CANDCAP) candbuf[(size_t)b * CANDCAP + p] = k;
    }
}

// ---------------- kernel 4: rank-sort candidates (16 blocks/batch, f64 keys) ----------------
__global__ __launch_bounds__(256)
void sort_kernel(const u64* __restrict__ candbuf, const u32* __restrict__ cntG,
                 u64* __restrict__ topkey) {
    int b = blockIdx.y, tid = threadIdx.x;
    int C = min((int)cntG[b], CANDCAP);
    int slice0 = blockIdx.x * 256;
    if (slice0 >= C) return;
    alignas(16) __shared__ double sd[CANDCAP + 2];
    const u64* cb = candbuf + (size_t)b * CANDCAP;
    for (int t2 = tid; t2 < C; t2 += 256) sd[t2] = (double)cb[t2];   // 48-bit keys: exact
    if (tid == 0) { sd[C] = -1.0; sd[C + 1] = -1.0; }               // pad (never > any key)
    __syncthreads();
    int i = slice0 + tid;
    if (i < C) {
        double ki = sd[i];
        int rank = 0;
        const double2* sd2 = (const double2*)sd;
        int C2 = ((C + 1) & ~1) >> 1;
        for (int j = 0; j < C2; ++j) {          // uniform j -> LDS broadcast
            double2 v2 = sd2[j];
            rank += (v2.x > ki) ? 1 : 0;
            rank += (v2.y > ki) ? 1 : 0;
        }
        if (rank < MAXD) topkey[(size_t)b * KPAD + rank] = cb[i];   // distinct keys: bijection
    }
}

// ---------------- kernel 5: gather winners (128 blocks) ----------------
__global__ __launch_bounds__(128)
void gather_kernel(Ptrs ptrs, const u64* __restrict__ topkey,
                   float4* __restrict__ traw, float* __restrict__ tscore,
                   float* __restrict__ tclsf, u32* __restrict__ validbits,
                   u32* __restrict__ maxcG) {
    #pragma clang fp contract(off)
    int b = blockIdx.y;
    int i = blockIdx.x * 128 + threadIdx.x;   // 0..1023
    float4 bx = make_float4(0.f, 0.f, 0.f, 0.f);
    float score = 0.f, clsf = 0.f;
    if (i < MAXD) {
        u64 key = topkey[(size_t)b * KPAD + i];
        int n = 65535 - (int)(key & 0xFFFFull);
        score = __uint_as_float((u32)(key >> 16));
        int mod = (n >= NMOD) ? 1 : 0;
        int nm = n - mod * NMOD;
        int l, pos, w, s, hw;
        level_of(nm, l, pos, w, s, hw);
        const float* clsP = ptrs.p[mod * 15 + l];
        const float* regP = ptrs.p[mod * 15 + 10 + l];
        const float* cbp = clsP + (size_t)b * 20 * hw + pos;
        const float* rb  = regP + (size_t)b * 4 * hw + pos;
        float cl[20];
        #pragma unroll
        for (int c = 0; c < 20; ++c) cl[c] = cbp[(size_t)c * hw];   // all loads batched
        float r0 = rb[0], r1 = rb[(size_t)hw], r2 = rb[(size_t)2 * hw], r3 = rb[(size_t)3 * hw];
        float best = -1.0f; int bi = 0;
        #pragma unroll
        for (int c = 0; c < 20; ++c) {
            float p = sigm(cl[c]);
            if (p > best) { best = p; bi = c; }
        }
        clsf = (float)(bi + 1);
        int xi = pos % w, yi = pos / w;
        float cx = (float)(xi * s + (s >> 1));
        float cy = (float)(yi * s + (s >> 1));
        bx.x = cx - r0; bx.y = cy - r1; bx.z = cx + r2; bx.w = cy + r3;
    }
    int valid = (i < MAXD) && (score >= 0.05f);
    if (valid) atomicOr(&validbits[b * 32 + (i >> 5)], 1u << (i & 31));
    float contrib = valid ? fmaxf(fmaxf(bx.x, bx.y), fmaxf(bx.z, bx.w)) : 0.0f;
    contrib = fmaxf(contrib, 0.0f);   // nonneg -> uint-bit atomicMax is order-correct
    #pragma unroll
    for (int off = 32; off > 0; off >>= 1) contrib = fmaxf(contrib, __shfl_down(contrib, off));
    if ((threadIdx.x & 63) == 0) atomicMax(&maxcG[b], __float_as_uint(contrib));
    size_t oo = (size_t)b * KPAD + i;
    traw[oo] = bx; tscore[oo] = score; tclsf[oo] = clsf;   // zeros for i >= MAXD
}

// ---------------- kernel 6: IoU>0.6 bitmask, upper-triangle units ----------------
// offset boxes + areas recomputed inline (bit-identical expressions everywhere).
#define SW(t) ((((t) & 31) << 3) | ((t) >> 5))
__global__ __launch_bounds__(64)
void mask_kernel(const float4* __restrict__ traw, const float* __restrict__ tclsf,
                 const u32* __restrict__ maxcG, u32* __restrict__ maskG) {
    #pragma clang fp contract(off)
    int u = blockIdx.x, b = blockIdx.y, tid = threadIdx.x;
    int g, wg;
    if (u < 128)      { g = u >> 2;                 wg = u & 3; }
    else if (u < 224) { int i2 = u - 128; g = 32 + i2 / 3;      wg = 1 + i2 % 3; }
    else if (u < 288) { int i2 = u - 224; g = 64 + (i2 >> 1);   wg = 2 + (i2 & 1); }
    else              { g = 96 + (u - 288);         wg = 3; }
    int i0 = g * 8, j0 = wg * 256;
    float m1 = __uint_as_float(maxcG[b]) + 1.0f;

    __shared__ float cx1[256], cy1[256], cx2[256], cy2[256], ca[256];
    for (int t = tid; t < 256; t += 64) {
        float4 f = traw[(size_t)b * KPAD + j0 + t];
        float o = __fmul_rn(tclsf[(size_t)b * KPAD + j0 + t], m1);
        float ox1 = __fadd_rn(f.x, o), oy1 = __fadd_rn(f.y, o);
        float ox2 = __fadd_rn(f.z, o), oy2 = __fadd_rn(f.w, o);
        float dw = ox2 - ox1 + 1.0f;
        float dh = oy2 - oy1 + 1.0f;
        int ts = SW(t);
        cx1[ts] = ox1; cy1[ts] = oy1; cx2[ts] = ox2; cy2[ts] = oy2;
        ca[ts] = __fmul_rn(dw, dh);
    }
    __syncthreads();

    int ir = tid >> 3, wr = tid & 7;
    int i = i0 + ir;
    float4 fi = traw[(size_t)b * KPAD + i];
    float oi = __fmul_rn(tclsf[(size_t)b * KPAD + i], m1);
    float ix1 = __fadd_rn(fi.x, oi), iy1 = __fadd_rn(fi.y, oi);
    float ix2 = __fadd_rn(fi.z, oi), iy2 = __fadd_rn(fi.w, oi);
    float dwi = ix2 - ix1 + 1.0f, dhi = iy2 - iy1 + 1.0f;
    float ai = __fmul_rn(dwi, dhi);
    u32 bits = 0;
    int jb = wr * 32;
    for (int jj = 0; jj < 32; ++jj) {
        int js = SW(jb + jj);
        float iw = fminf(ix2, cx2[js]) - fmaxf(ix1, cx1[js]) + 1.0f;
        iw = fmaxf(iw, 0.0f);
        float ih = fminf(iy2, cy2[js]) - fmaxf(iy1, cy1[js]) + 1.0f;
        ih = fmaxf(ih, 0.0f);
        float inter = iw * ih;
        float denom = (ai + ca[js]) - inter;
        float iou = inter / denom;
        bits |= (iou > 0.6f) ? (1u << jj) : 0u;
    }
    maskG[((size_t)b * KPAD + i) * 32 + wg * 8 + wr] = bits;
}

// ---------------- kernel 7: greedy scan (1 wave/batch, depth-16 prefetch) + outputs ----------------
__global__ __launch_bounds__(64)
void scan_out_kernel(const u32* __restrict__ maskG, const u32* __restrict__ validbits,
                     const float4* __restrict__ traw, const float* __restrict__ tscore,
                     const float* __restrict__ tclsf, float* __restrict__ out) {
    int b = blockIdx.x, lane = threadIdx.x;
    int lw = lane & 31;
    const u32* mrow = maskG + (size_t)b * KPAD * 32;
    u32 vreg = (lane < 32) ? validbits[b * 32 + lane] : 0u;
    u32 removed = 0u, keepw = 0u;
    u32 mA[8], mB[8];
    #pragma unroll
    for (int d = 0; d < 8; ++d) {
        mA[d] = mrow[(size_t)d * 32 + lw];
        mB[d] = mrow[(size_t)(d + 8) * 32 + lw];
    }
    auto step8 = [&](int base, u32* ms) {
        #pragma unroll
        for (int d = 0; d < 8; ++d) {
            int i = base + d;
            int wi = i >> 5, bi2 = i & 31;
            u32 rw = (u32)__builtin_amdgcn_readlane((int)removed, wi);
            u32 vw = (u32)__builtin_amdgcn_readlane((int)vreg, wi);
            u32 k = ((vw >> bi2) & 1u) & (~(rw >> bi2) & 1u);
            if (k) removed |= ms[d];
            if (lane == wi) keepw |= (k << bi2);
            ms[d] = mrow[(size_t)(i + 16) * 32 + lw];
        }
    };
    for (int t = 0; t < 62; ++t) { step8(t * 16, mA); step8(t * 16 + 8, mB); }
    step8(992, mA);

    __shared__ u32 keeps[32];
    if (lane < 32) keeps[lane] = keepw;
    __syncthreads();
    const int BQ = BATCH * MAXD;
    for (int s2 = lane; s2 < MAXD; s2 += 64) {
        u32 kf = (keeps[s2 >> 5] >> (s2 & 31)) & 1u;
        size_t oo = (size_t)b * KPAD + s2;
        float score = tscore[oo];
        float clsf = tclsf[oo];
        float4 bx = traw[oo];
        float x1 = fminf(fmaxf(bx.x, 0.f), 1279.f);
        float y1 = fminf(fmaxf(bx.y, 0.f), 1023.f);
        float x2 = fminf(fmaxf(bx.z, 0.f), 1279.f);
        float y2 = fminf(fmaxf(bx.w, 0.f), 1023.f);
        int base = b * MAXD + s2;
        out[base] = kf ? score : 0.0f;
        out[BQ + base] = kf ? clsf : 0.0f;
        float* ob = out + 2 * BQ + (size_t)base * 4;
        ob[0] = kf ? x1 : 0.f; ob[1] = kf ? y1 : 0.f;
        ob[2] = kf ? x2 : 0.f; ob[3] = kf ? y2 : 0.f;
        out[6 * BQ + base] = kf ? 1.0f : 0.0f;
    }
}

// ---------------- launch ----------------
extern "C" void kernel_launch(void* const* d_in, const int* in_sizes, int n_in,
                              void* d_out, int out_size, void* d_ws, size_t ws_size,
                              hipStream_t stream) {
    Ptrs ptrs;
    for (int i = 0; i < 30; ++i) ptrs.p[i] = (const float*)d_in[i];

    char* ws = (char*)d_ws;
    u64*        keyAll    = (u64*)       (ws + OFF_KEY);
    ulonglong2* keyAll2   = (ulonglong2*)(ws + OFF_KEY);
    u64*        topkey    = (u64*)       (ws + OFF_TOPK);
    u64*        candbuf   = (u64*)       (ws + OFF_CAND);
    float4*     traw      = (float4*)    (ws + OFF_TRAW);
    float*      tscore    = (float*)     (ws + OFF_TSCORE);
    float*      tclsf     = (float*)     (ws + OFF_TCLSF);
    int*        selB1     = (int*)       (ws + OFF_SELB);
    u32*        hist      = (u32*)       (ws + OFF_HIST);
    u32*        maskG     = (u32*)       (ws + OFF_MASK);
    u32*        cntG      = (u32*)       (ws + OFF_CNT);
    u32*        maxcG     = (u32*)       (ws + OFF_MAXC);
    u32*        validbits = (u32*)       (ws + OFF_VALID);
    float*      out       = (float*)d_out;

    hipMemsetAsync(ws + OFF_HIST, 0, SZ_HIST, stream);
    hipMemsetAsync(ws + OFF_CNT, 0, SZ_CNT + SZ_MAXC + SZ_VAL, stream);

    decode_kernel<<<dim3((NTOT / 4 + 255) / 256, BATCH), 256, 0, stream>>>(ptrs, keyAll2, hist);
    scanB1_kernel<<<BATCH, 1024, 0, stream>>>(hist, selB1);
    compact_kernel<<<dim3((NTOT + 255) / 256, BATCH), 256, 0, stream>>>(keyAll, selB1, cntG, candbuf);
    sort_kernel<<<dim3(CANDCAP / 256 / 1.5 > 16 ? 16 : 16, BATCH), 256, 0, stream>>>(candbuf, cntG, topkey);
    gather_kernel<<<dim3(8, BATCH), 128, 0, stream>>>(ptrs, topkey, traw, tscore, tclsf,
                                                      validbits, maxcG);
    mask_kernel<<<dim3(320, BATCH), 64, 0, stream>>>(traw, tclsf, maxcG, maskG);
    scan_out_kernel<<<BATCH, 64, 0, stream>>>(maskG, validbits, traw, tscore, tclsf, out);
}

// Round 5
// 305.413 us; speedup vs baseline: 1.5478x; 1.5478x over previous
//
#include <hip/hip_runtime.h>
#include <hip/hip_bf16.h>

typedef unsigned long long u64;
typedef unsigned int u32;

#define NTOT    54560   // anchors per batch (r + i)
#define NMOD    27280   // anchors per modality
#define BATCH   16
#define KPAD    1024
#define MAXD    1000
#define NBIN    16384   // score-bits >> 16
#define CANDCAP 6144
#define NB      214     // ceil(NTOT/256) blocks for compact passes
#define HCOPY   4       // spread histogram copies

struct Ptrs { const float* p[30]; };

// ---------------- workspace layout (16B aligned) ----------------
constexpr size_t SZ_KEY   = (size_t)BATCH * NTOT * 8;          // 6.98 MB
constexpr size_t SZ_TOPK  = (size_t)BATCH * KPAD * 8;          // 128 KB
constexpr size_t SZ_CAND  = (size_t)BATCH * CANDCAP * 8;       // 768 KB
constexpr size_t SZ_TRAW  = (size_t)BATCH * KPAD * 16;         // 256 KB
constexpr size_t SZ_T1    = (size_t)BATCH * KPAD * 4;          // 64 KB
constexpr size_t SZ_SELB  = 64;
constexpr size_t SZ_BCNT  = (size_t)BATCH * NB * 4;            // 13.7 KB
constexpr size_t SZ_CNTG  = 64;
constexpr size_t SZ_MAXC  = (size_t)BATCH * 32 * 4;            // padded: 128B/batch
constexpr size_t SZ_VALID = (size_t)BATCH * 32 * 4;
constexpr size_t SZ_HIST8 = (size_t)HCOPY * BATCH * NBIN * 4;  // 4 MB
constexpr size_t SZ_MASK  = (size_t)BATCH * KPAD * 32 * 4;     // 2 MB

constexpr size_t OFF_KEY    = 0;
constexpr size_t OFF_TOPK   = OFF_KEY   + SZ_KEY;
constexpr size_t OFF_CAND   = OFF_TOPK  + SZ_TOPK;
constexpr size_t OFF_TRAW   = OFF_CAND  + SZ_CAND;
constexpr size_t OFF_TSCORE = OFF_TRAW  + SZ_TRAW;
constexpr size_t OFF_TCLSF  = OFF_TSCORE+ SZ_T1;
constexpr size_t OFF_SELB   = OFF_TCLSF + SZ_T1;
constexpr size_t OFF_BCNT   = OFF_SELB  + SZ_SELB;
constexpr size_t OFF_BOFF   = OFF_BCNT  + SZ_BCNT;
constexpr size_t OFF_CNTG   = OFF_BOFF  + SZ_BCNT;
constexpr size_t OFF_MAXC   = OFF_CNTG  + SZ_CNTG;
constexpr size_t OFF_VALID  = OFF_MAXC  + SZ_MAXC;
constexpr size_t OFF_HIST8  = ((OFF_VALID + SZ_VALID + 255) & ~(size_t)255);
// merged hist = copy 0 (in-place); maskG overlays copies 2..3 (dead after merge)
constexpr size_t OFF_MASK   = OFF_HIST8 + 2 * (size_t)BATCH * NBIN * 4;

__device__ inline void level_of(int nm, int& l, int& pos, int& w, int& s, int& hw) {
    if (nm < 20480)      { l = 0; pos = nm;         w = 160; s = 8;   hw = 20480; }
    else if (nm < 25600) { l = 1; pos = nm - 20480; w = 80;  s = 16;  hw = 5120; }
    else if (nm < 26880) { l = 2; pos = nm - 25600; w = 40;  s = 32;  hw = 1280; }
    else if (nm < 27200) { l = 3; pos = nm - 26880; w = 20;  s = 64;  hw = 320; }
    else                 { l = 4; pos = nm - 27200; w = 10;  s = 128; hw = 80; }
}

__device__ inline float sigm(float x) { return 1.0f / (1.0f + expf(-x)); }

// ---------------- kernel 1: decode scores -> keys + spread histograms ----------------
// lane pair (2t, 2t+1) handles one float4-anchor-group; each lane does 10 channels,
// combined via shfl_xor(1). max-before-sigmoid: bitwise equal (monotone).
__global__ __launch_bounds__(256)
void decode_kernel(Ptrs ptrs, ulonglong2* __restrict__ keyAll2, u32* __restrict__ hist8) {
    int tt = blockIdx.x * 256 + threadIdx.x;
    int b = blockIdx.y;
    if (tt >= NTOT / 2) return;
    int g = tt >> 1, half = tt & 1;
    int n0 = g * 4;
    int mod = (n0 >= NMOD) ? 1 : 0;
    int nm = n0 - mod * NMOD;
    int l, pos, w, s, hw;
    level_of(nm, l, pos, w, s, hw);
    (void)w; (void)s;
    const float* clsP = ptrs.p[mod * 15 + l];
    const float* cntP = ptrs.p[mod * 15 + 5 + l];
    const float4* cb = (const float4*)(clsP + (size_t)b * 20 * hw + pos);
    int hw4 = hw >> 2;
    int c0 = half * 10;
    float4 mx = cb[(size_t)c0 * hw4];
    #pragma unroll
    for (int c = 1; c < 10; ++c) {
        float4 v = cb[(size_t)(c0 + c) * hw4];
        mx.x = fmaxf(mx.x, v.x); mx.y = fmaxf(mx.y, v.y);
        mx.z = fmaxf(mx.z, v.z); mx.w = fmaxf(mx.w, v.w);
    }
    mx.x = fmaxf(mx.x, __shfl_xor(mx.x, 1));
    mx.y = fmaxf(mx.y, __shfl_xor(mx.y, 1));
    mx.z = fmaxf(mx.z, __shfl_xor(mx.z, 1));
    mx.w = fmaxf(mx.w, __shfl_xor(mx.w, 1));
    float4 cv = *(const float4*)(cntP + (size_t)b * hw + pos);

    float ma = half ? mx.z : mx.x;
    float mb = half ? mx.w : mx.y;
    float ca = half ? cv.z : cv.x;
    float cbv= half ? cv.w : cv.y;
    int a0 = n0 + half * 2;
    u32 s0 = __float_as_uint(sqrtf(__fmul_rn(sigm(ma), sigm(ca))));
    u32 s1 = __float_as_uint(sqrtf(__fmul_rn(sigm(mb), sigm(cbv))));
    ulonglong2 kk;
    kk.x = ((u64)s0 << 16) | (u64)(65535 - a0);
    kk.y = ((u64)s1 << 16) | (u64)(65535 - (a0 + 1));
    keyAll2[(((size_t)b * NTOT + n0) >> 1) + half] = kk;

    u32* hb = hist8 + (size_t)(blockIdx.x & (HCOPY - 1)) * (BATCH * NBIN) + (size_t)b * NBIN;
    atomicAdd(&hb[s0 >> 16], 1u);
    atomicAdd(&hb[s1 >> 16], 1u);
}

// ---------------- kernel 2: merge histogram copies (into copy 0) ----------------
__global__ __launch_bounds__(256)
void merge_hist_kernel(u32* __restrict__ hist8) {
    int idx = blockIdx.x * 256 + threadIdx.x;   // 0 .. BATCH*NBIN-1
    u32 s = hist8[idx];
    #pragma unroll
    for (int c = 1; c < HCOPY; ++c) s += hist8[(size_t)c * (BATCH * NBIN) + idx];
    hist8[idx] = s;
}

// ---------------- kernel 3: per-batch threshold bin B1 ----------------
__global__ __launch_bounds__(1024)
void scanB1_kernel(const u32* __restrict__ histM, int* __restrict__ selB1) {
    int b = blockIdx.x, tid = threadIdx.x;
    __shared__ u32 ps[1024];
    const u32* h = histM + (size_t)b * NBIN;
    u32 loc[16]; u32 sum = 0;
    #pragma unroll
    for (int j = 0; j < 16; ++j) { loc[j] = h[NBIN - 1 - (tid * 16 + j)]; sum += loc[j]; }
    ps[tid] = sum;
    __syncthreads();
    for (int off = 1; off < 1024; off <<= 1) {
        u32 v = (tid >= off) ? ps[tid - off] : 0u;
        __syncthreads();
        ps[tid] += v;
        __syncthreads();
    }
    u32 incl = ps[tid], excl = incl - sum;
    if (excl < (u32)MAXD && incl >= (u32)MAXD) {
        u32 c = excl;
        #pragma unroll
        for (int j = 0; j < 16; ++j) {
            c += loc[j];
            if (c >= (u32)MAXD) { selB1[b] = NBIN - 1 - (tid * 16 + j); break; }
        }
    }
}

// ---------------- kernel 4a: per-block candidate counts (no atomics) ----------------
__global__ __launch_bounds__(256)
void compact_count_kernel(const u64* __restrict__ keyAll, const int* __restrict__ selB1,
                          u32* __restrict__ blockCnt) {
    int n = blockIdx.x * 256 + threadIdx.x;
    int b = blockIdx.y;
    bool pred = false;
    if (n < NTOT) pred = (int)(keyAll[(size_t)b * NTOT + n] >> 32) >= selB1[b];
    u64 ball = __ballot(pred);
    __shared__ u32 wcnt[4];
    int wid = threadIdx.x >> 6;
    if ((threadIdx.x & 63) == 0) wcnt[wid] = (u32)__popcll(ball);
    __syncthreads();
    if (threadIdx.x == 0)
        blockCnt[b * NB + blockIdx.x] = wcnt[0] + wcnt[1] + wcnt[2] + wcnt[3];
}

// ---------------- kernel 4b: exclusive scan of block counts (1 block) ----------------
__global__ __launch_bounds__(1024)
void offset_scan_kernel(const u32* __restrict__ blockCnt, u32* __restrict__ blockOff,
                        u32* __restrict__ cntG) {
    int lane = threadIdx.x & 63;
    int b = threadIdx.x >> 6;      // wave per batch
    u32 carry = 0;
    for (int ch = 0; ch < 4; ++ch) {
        int idx = ch * 64 + lane;
        u32 v = (idx < NB) ? blockCnt[b * NB + idx] : 0u;
        u32 orig = v;
        #pragma unroll
        for (int off = 1; off < 64; off <<= 1) {
            u32 t2 = (u32)__shfl_up((int)v, off);
            if (lane >= off) v += t2;
        }
        if (idx < NB) blockOff[b * NB + idx] = carry + (v - orig);
        carry += (u32)__shfl((int)v, 63);
    }
    if (lane == 0) cntG[b] = carry;
}

// ---------------- kernel 4c: compact write at exact offsets (no atomics) ----------------
__global__ __launch_bounds__(256)
void compact_write_kernel(const u64* __restrict__ keyAll, const int* __restrict__ selB1,
                          const u32* __restrict__ blockOff, u64* __restrict__ candbuf) {
    int n = blockIdx.x * 256 + threadIdx.x;
    int b = blockIdx.y;
    u64 k = 0; bool pred = false;
    if (n < NTOT) {
        k = keyAll[(size_t)b * NTOT + n];
        pred = (int)(k >> 32) >= selB1[b];
    }
    u64 ball = __ballot(pred);
    int lane = threadIdx.x & 63, wid = threadIdx.x >> 6;
    __shared__ u32 wcnt[4];
    if (lane == 0) wcnt[wid] = (u32)__popcll(ball);
    __syncthreads();
    u32 wbase = 0;
    for (int i = 0; i < 4; ++i) if (i < wid) wbase += wcnt[i];
    if (pred) {
        u32 rank = (u32)__popcll(ball & ((1ull << lane) - 1ull));
        u32 dst = blockOff[b * NB + blockIdx.x] + wbase + rank;
        if (dst < CANDCAP) candbuf[(size_t)b * CANDCAP + dst] = k;
    }
}

// ---------------- kernel 5: rank-sort candidates (f64 keys, LDS broadcast) ----------------
__global__ __launch_bounds__(256)
void sort_kernel(const u64* __restrict__ candbuf, const u32* __restrict__ cntG,
                 u64* __restrict__ topkey) {
    int b = blockIdx.y, tid = threadIdx.x;
    int C = min((int)cntG[b], CANDCAP);
    int slice0 = blockIdx.x * 256;
    if (slice0 >= C) return;
    alignas(16) __shared__ double sd[CANDCAP + 2];
    const u64* cb = candbuf + (size_t)b * CANDCAP;
    for (int t2 = tid; t2 < C; t2 += 256) sd[t2] = (double)cb[t2];   // 48-bit keys exact
    if (tid == 0) { sd[C] = -1.0; sd[C + 1] = -1.0; }
    __syncthreads();
    int i = slice0 + tid;
    if (i < C) {
        double ki = sd[i];
        int rank = 0;
        const double2* sd2 = (const double2*)sd;
        int C2 = ((C + 1) & ~1) >> 1;
        for (int j = 0; j < C2; ++j) {
            double2 v2 = sd2[j];
            rank += (v2.x > ki) ? 1 : 0;
            rank += (v2.y > ki) ? 1 : 0;
        }
        if (rank < MAXD) topkey[(size_t)b * KPAD + rank] = cb[i];
    }
}

// ---------------- kernel 6: gather winners (pair-split channels, no hot atomics) ----------------
__global__ __launch_bounds__(128)
void gather_kernel(Ptrs ptrs, const u64* __restrict__ topkey,
                   float4* __restrict__ traw, float* __restrict__ tscore,
                   float* __restrict__ tclsf, u32* __restrict__ validwords,
                   u32* __restrict__ maxcG) {
    #pragma clang fp contract(off)
    int b = blockIdx.y;
    int tid = threadIdx.x;
    int half = tid & 1;
    int i = blockIdx.x * 64 + (tid >> 1);   // winner 0..1023 (pairs share i)
    int active = (i < MAXD);

    float score = 0.f;
    float best = -1.0f; int bi = 0;
    float ra = 0.f, rb2 = 0.f;
    int pos = 0, w = 1, s = 0;
    if (active) {
        u64 key = topkey[(size_t)b * KPAD + i];
        int n = 65535 - (int)(key & 0xFFFFull);
        score = __uint_as_float((u32)(key >> 16));
        int mod = (n >= NMOD) ? 1 : 0;
        int nm = n - mod * NMOD;
        int l, hw;
        level_of(nm, l, pos, w, s, hw);
        const float* clsP = ptrs.p[mod * 15 + l];
        const float* regP = ptrs.p[mod * 15 + 10 + l];
        const float* cbp = clsP + (size_t)b * 20 * hw + pos;
        const float* rbp = regP + (size_t)b * 4 * hw + pos;
        float cl[10];
        int c0 = half * 10;
        #pragma unroll
        for (int c = 0; c < 10; ++c) cl[c] = cbp[(size_t)(c0 + c) * hw];
        ra  = rbp[(size_t)(half * 2) * hw];
        rb2 = rbp[(size_t)(half * 2 + 1) * hw];
        #pragma unroll
        for (int c = 0; c < 10; ++c) {
            float p = sigm(cl[c]);
            if (p > best) { best = p; bi = c0 + c; }
        }
    }
    // combine halves (partner lane always same i -> same activity)
    float po  = __shfl_xor(best, 1);
    int   bio = __shfl_xor(bi, 1);
    float rao = __shfl_xor(ra, 1);
    float rbo = __shfl_xor(rb2, 1);
    if (half == 0) { if (po > best)  { best = po; bi = bio; } }
    else           { if (po >= best) { best = po; bi = bio; } }
    float clsf = active ? (float)(bi + 1) : 0.f;
    float r0 = half ? rao : ra,  r1 = half ? rbo : rb2;
    float r2 = half ? ra  : rao, r3 = half ? rb2 : rbo;

    float4 bx = make_float4(0.f, 0.f, 0.f, 0.f);
    if (active) {
        int xi = pos % w, yi = pos / w;
        float cx = (float)(xi * s + (s >> 1));
        float cy = (float)(yi * s + (s >> 1));
        bx.x = cx - r0; bx.y = cy - r1; bx.z = cx + r2; bx.w = cy + r3;
    }
    int valid = active && (score >= 0.05f) && (half == 0);
    float contrib = valid ? fmaxf(0.0f, fmaxf(fmaxf(bx.x, bx.y), fmaxf(bx.z, bx.w))) : 0.0f;
    // wave-reduce maxc
    float red = contrib;
    #pragma unroll
    for (int off = 32; off > 0; off >>= 1) red = fmaxf(red, __shfl_down(red, off));
    if ((tid & 63) == 0) atomicMax(&maxcG[b * 32], __float_as_uint(red));
    // valid word: winner j in wave <-> ballot bit 2j
    u64 ball = __ballot(valid != 0);
    if ((tid & 63) == 0) {
        u32 word = 0;
        for (int j = 0; j < 32; ++j) word |= (u32)((ball >> (2 * j)) & 1ull) << j;
        validwords[b * 32 + blockIdx.x * 2 + (tid >> 6)] = word;
    }
    if (half == 0) {
        size_t oo = (size_t)b * KPAD + i;
        traw[oo] = bx; tscore[oo] = score; tclsf[oo] = clsf;
    }
}

// ---------------- kernel 7: IoU>0.6 bitmask, upper-triangle units ----------------
#define SW(t) ((((t) & 31) << 3) | ((t) >> 5))
__global__ __launch_bounds__(64)
void mask_kernel(const float4* __restrict__ traw, const float* __restrict__ tclsf,
                 const u32* __restrict__ maxcG, u32* __restrict__ maskG) {
    #pragma clang fp contract(off)
    int u = blockIdx.x, b = blockIdx.y, tid = threadIdx.x;
    int g, wg;
    if (u < 128)      { g = u >> 2;                 wg = u & 3; }
    else if (u < 224) { int i2 = u - 128; g = 32 + i2 / 3;      wg = 1 + i2 % 3; }
    else if (u < 288) { int i2 = u - 224; g = 64 + (i2 >> 1);   wg = 2 + (i2 & 1); }
    else              { g = 96 + (u - 288);         wg = 3; }
    int i0 = g * 8, j0 = wg * 256;
    float m1 = __uint_as_float(maxcG[b * 32]) + 1.0f;

    __shared__ float cx1[256], cy1[256], cx2[256], cy2[256], ca[256];
    for (int t = tid; t < 256; t += 64) {
        float4 f = traw[(size_t)b * KPAD + j0 + t];
        float o = __fmul_rn(tclsf[(size_t)b * KPAD + j0 + t], m1);
        float ox1 = __fadd_rn(f.x, o), oy1 = __fadd_rn(f.y, o);
        float ox2 = __fadd_rn(f.z, o), oy2 = __fadd_rn(f.w, o);
        float dw = ox2 - ox1 + 1.0f;
        float dh = oy2 - oy1 + 1.0f;
        int ts = SW(t);
        cx1[ts] = ox1; cy1[ts] = oy1; cx2[ts] = ox2; cy2[ts] = oy2;
        ca[ts] = __fmul_rn(dw, dh);
    }
    __syncthreads();

    int ir = tid >> 3, wr = tid & 7;
    int i = i0 + ir;
    float4 fi = traw[(size_t)b * KPAD + i];
    float oi = __fmul_rn(tclsf[(size_t)b * KPAD + i], m1);
    float ix1 = __fadd_rn(fi.x, oi), iy1 = __fadd_rn(fi.y, oi);
    float ix2 = __fadd_rn(fi.z, oi), iy2 = __fadd_rn(fi.w, oi);
    float dwi = ix2 - ix1 + 1.0f, dhi = iy2 - iy1 + 1.0f;
    float ai = __fmul_rn(dwi, dhi);
    u32 bits = 0;
    int jb = wr * 32;
    for (int jj = 0; jj < 32; ++jj) {
        int js = SW(jb + jj);
        float iw = fminf(ix2, cx2[js]) - fmaxf(ix1, cx1[js]) + 1.0f;
        iw = fmaxf(iw, 0.0f);
        float ih = fminf(iy2, cy2[js]) - fmaxf(iy1, cy1[js]) + 1.0f;
        ih = fmaxf(ih, 0.0f);
        float inter = iw * ih;
        float denom = (ai + ca[js]) - inter;
        float iou = inter / denom;
        bits |= (iou > 0.6f) ? (1u << jj) : 0u;
    }
    maskG[((size_t)b * KPAD + i) * 32 + wg * 8 + wr] = bits;
}

// ---------------- kernel 8: greedy scan (1 wave/batch, depth-16 prefetch) + outputs ----------------
__global__ __launch_bounds__(64)
void scan_out_kernel(const u32* __restrict__ maskG, const u32* __restrict__ validbits,
                     const float4* __restrict__ traw, const float* __restrict__ tscore,
                     const float* __restrict__ tclsf, float* __restrict__ out) {
    int b = blockIdx.x, lane = threadIdx.x;
    int lw = lane & 31;
    const u32* mrow = maskG + (size_t)b * KPAD * 32;
    u32 vreg = (lane < 32) ? validbits[b * 32 + lane] : 0u;
    u32 removed = 0u, keepw = 0u;
    u32 mA[8], mB[8];
    #pragma unroll
    for (int d = 0; d < 8; ++d) {
        mA[d] = mrow[(size_t)d * 32 + lw];
        mB[d] = mrow[(size_t)(d + 8) * 32 + lw];
    }
    auto step8 = [&](int base, u32* ms) {
        #pragma unroll
        for (int d = 0; d < 8; ++d) {
            int i = base + d;
            int wi = i >> 5, bi2 = i & 31;
            u32 rw = (u32)__builtin_amdgcn_readlane((int)removed, wi);
            u32 vw = (u32)__builtin_amdgcn_readlane((int)vreg, wi);
            u32 k = ((vw >> bi2) & 1u) & (~(rw >> bi2) & 1u);
            if (k) removed |= ms[d];
            if (lane == wi) keepw |= (k << bi2);
            ms[d] = mrow[(size_t)(i + 16) * 32 + lw];
        }
    };
    for (int t = 0; t < 62; ++t) { step8(t * 16, mA); step8(t * 16 + 8, mB); }
    step8(992, mA);

    __shared__ u32 keeps[32];
    if (lane < 32) keeps[lane] = keepw;
    __syncthreads();
    const int BQ = BATCH * MAXD;
    for (int s2 = lane; s2 < MAXD; s2 += 64) {
        u32 kf = (keeps[s2 >> 5] >> (s2 & 31)) & 1u;
        size_t oo = (size_t)b * KPAD + s2;
        float score = tscore[oo];
        float clsf = tclsf[oo];
        float4 bx = traw[oo];
        float x1 = fminf(fmaxf(bx.x, 0.f), 1279.f);
        float y1 = fminf(fmaxf(bx.y, 0.f), 1023.f);
        float x2 = fminf(fmaxf(bx.z, 0.f), 1279.f);
        float y2 = fminf(fmaxf(bx.w, 0.f), 1023.f);
        int base = b * MAXD + s2;
        out[base] = kf ? score : 0.0f;
        out[BQ + base] = kf ? clsf : 0.0f;
        float* ob = out + 2 * BQ + (size_t)base * 4;
        ob[0] = kf ? x1 : 0.f; ob[1] = kf ? y1 : 0.f;
        ob[2] = kf ? x2 : 0.f; ob[3] = kf ? y2 : 0.f;
        out[6 * BQ + base] = kf ? 1.0f : 0.0f;
    }
}

// ---------------- launch ----------------
extern "C" void kernel_launch(void* const* d_in, const int* in_sizes, int n_in,
                              void* d_out, int out_size, void* d_ws, size_t ws_size,
                              hipStream_t stream) {
    Ptrs ptrs;
    for (int i = 0; i < 30; ++i) ptrs.p[i] = (const float*)d_in[i];

    char* ws = (char*)d_ws;
    u64*        keyAll    = (u64*)       (ws + OFF_KEY);
    ulonglong2* keyAll2   = (ulonglong2*)(ws + OFF_KEY);
    u64*        topkey    = (u64*)       (ws + OFF_TOPK);
    u64*        candbuf   = (u64*)       (ws + OFF_CAND);
    float4*     traw      = (float4*)    (ws + OFF_TRAW);
    float*      tscore    = (float*)     (ws + OFF_TSCORE);
    float*      tclsf     = (float*)     (ws + OFF_TCLSF);
    int*        selB1     = (int*)       (ws + OFF_SELB);
    u32*        blockCnt  = (u32*)       (ws + OFF_BCNT);
    u32*        blockOff  = (u32*)       (ws + OFF_BOFF);
    u32*        cntG      = (u32*)       (ws + OFF_CNTG);
    u32*        maxcG     = (u32*)       (ws + OFF_MAXC);
    u32*        validbits = (u32*)       (ws + OFF_VALID);
    u32*        hist8     = (u32*)       (ws + OFF_HIST8);
    u32*        maskG     = (u32*)       (ws + OFF_MASK);
    float*      out       = (float*)d_out;

    hipMemsetAsync(ws + OFF_HIST8, 0, SZ_HIST8, stream);
    hipMemsetAsync(ws + OFF_MAXC, 0, SZ_MAXC, stream);

    decode_kernel<<<dim3((NTOT / 2 + 255) / 256, BATCH), 256, 0, stream>>>(ptrs, keyAll2, hist8);
    merge_hist_kernel<<<(BATCH * NBIN) / 256, 256, 0, stream>>>(hist8);
    scanB1_kernel<<<BATCH, 1024, 0, stream>>>(hist8, selB1);
    compact_count_kernel<<<dim3(NB, BATCH), 256, 0, stream>>>(keyAll, selB1, blockCnt);
    offset_scan_kernel<<<1, 1024, 0, stream>>>(blockCnt, blockOff, cntG);
    compact_write_kernel<<<dim3(NB, BATCH), 256, 0, stream>>>(keyAll, selB1, blockOff, candbuf);
    sort_kernel<<<dim3(CANDCAP / 256, BATCH), 256, 0, stream>>>(candbuf, cntG, topkey);
    gather_kernel<<<dim3(16, BATCH), 128, 0, stream>>>(ptrs, topkey, traw, tscore, tclsf,
                                                       validbits, maxcG);
    mask_kernel<<<dim3(320, BATCH), 64, 0, stream>>>(traw, tclsf, maxcG, maskG);
    scan_out_kernel<<<BATCH, 64, 0, stream>>>(maskG, validbits, traw, tscore, tclsf, out);
}

// Round 6
// 301.615 us; speedup vs baseline: 1.5673x; 1.0126x over previous
//
#include <hip/hip_runtime.h>
#include <hip/hip_bf16.h>

typedef unsigned long long u64;
typedef unsigned int u32;

#define NTOT    54560   // anchors per batch (r + i)
#define NMOD    27280   // anchors per modality
#define BATCH   16
#define KPAD    1024
#define MAXD    1000
#define NBIN    16384   // score-bits >> 16
#define CANDCAP 6144
#define NB      214     // ceil(NTOT/256)
#define HCOPY   4       // spread histogram copies

struct Ptrs { const float* p[30]; };

// ---------------- workspace layout (16B aligned) ----------------
constexpr size_t SZ_KEY   = (size_t)BATCH * NTOT * 8;          // 6.98 MB
constexpr size_t SZ_TOPK  = (size_t)BATCH * KPAD * 8;
constexpr size_t SZ_CAND  = (size_t)BATCH * CANDCAP * 8;
constexpr size_t SZ_TRAW  = (size_t)BATCH * KPAD * 16;
constexpr size_t SZ_T1    = (size_t)BATCH * KPAD * 4;
constexpr size_t SZ_SELB  = 64;
constexpr size_t SZ_CNTG  = (size_t)BATCH * 16 * 4;            // 64B-padded counters
constexpr size_t SZ_MAXC  = (size_t)BATCH * 32 * 4;
constexpr size_t SZ_VALID = (size_t)BATCH * 32 * 4;
constexpr size_t SZ_HIST8 = (size_t)HCOPY * BATCH * NBIN * 4;  // 4 MB
constexpr size_t SZ_MASK  = (size_t)BATCH * KPAD * 32 * 4;     // 2 MB

constexpr size_t OFF_KEY    = 0;
constexpr size_t OFF_TOPK   = OFF_KEY   + SZ_KEY;
constexpr size_t OFF_CAND   = OFF_TOPK  + SZ_TOPK;
constexpr size_t OFF_TRAW   = OFF_CAND  + SZ_CAND;
constexpr size_t OFF_TSCORE = OFF_TRAW  + SZ_TRAW;
constexpr size_t OFF_TCLSF  = OFF_TSCORE+ SZ_T1;
constexpr size_t OFF_SELB   = OFF_TCLSF + SZ_T1;
// single zeroed region: [CNTG | MAXC | VALID | pad | HIST8]
constexpr size_t OFF_CNTG   = OFF_SELB  + SZ_SELB;
constexpr size_t OFF_MAXC   = OFF_CNTG  + SZ_CNTG;
constexpr size_t OFF_VALID  = OFF_MAXC  + SZ_MAXC;
constexpr size_t OFF_HIST8  = ((OFF_VALID + SZ_VALID + 255) & ~(size_t)255);
constexpr size_t SZ_ZERO    = OFF_HIST8 + SZ_HIST8 - OFF_CNTG;
// maskG overlays hist copies 2..3 (dead after scanB1)
constexpr size_t OFF_MASK   = OFF_HIST8 + 2 * (size_t)BATCH * NBIN * 4;

__device__ inline void level_of(int nm, int& l, int& pos, int& w, int& s, int& hw) {
    if (nm < 20480)      { l = 0; pos = nm;         w = 160; s = 8;   hw = 20480; }
    else if (nm < 25600) { l = 1; pos = nm - 20480; w = 80;  s = 16;  hw = 5120; }
    else if (nm < 26880) { l = 2; pos = nm - 25600; w = 40;  s = 32;  hw = 1280; }
    else if (nm < 27200) { l = 3; pos = nm - 26880; w = 20;  s = 64;  hw = 320; }
    else                 { l = 4; pos = nm - 27200; w = 10;  s = 128; hw = 80; }
}

__device__ inline float sigm(float x) { return 1.0f / (1.0f + expf(-x)); }

// ---------------- kernel 1: decode scores -> keys + spread histograms ----------------
// lane pair handles one float4 anchor-group; 10 channels per lane, combined via shfl.
// __launch_bounds__(256,4): VGPR cap 128 so all 10 loads batch into ONE vmcnt round-trip.
__global__ __launch_bounds__(256, 4)
void decode_kernel(Ptrs ptrs, ulonglong2* __restrict__ keyAll2, u32* __restrict__ hist8) {
    int tt = blockIdx.x * 256 + threadIdx.x;
    int b = blockIdx.y;
    if (tt >= NTOT / 2) return;
    int g = tt >> 1, half = tt & 1;
    int n0 = g * 4;
    int mod = (n0 >= NMOD) ? 1 : 0;
    int nm = n0 - mod * NMOD;
    int l, pos, w, s, hw;
    level_of(nm, l, pos, w, s, hw);
    (void)w; (void)s;
    const float* clsP = ptrs.p[mod * 15 + l];
    const float* cntP = ptrs.p[mod * 15 + 5 + l];
    const float4* cb = (const float4*)(clsP + (size_t)b * 20 * hw + pos);
    int hw4 = hw >> 2;
    int c0 = half * 10;
    float4 v[10];
    #pragma unroll
    for (int c = 0; c < 10; ++c) v[c] = cb[(size_t)(c0 + c) * hw4];
    float4 cv = *(const float4*)(cntP + (size_t)b * hw + pos);

    float4 mx = v[0];
    #pragma unroll
    for (int c = 1; c < 10; ++c) {
        mx.x = fmaxf(mx.x, v[c].x); mx.y = fmaxf(mx.y, v[c].y);
        mx.z = fmaxf(mx.z, v[c].z); mx.w = fmaxf(mx.w, v[c].w);
    }
    mx.x = fmaxf(mx.x, __shfl_xor(mx.x, 1));
    mx.y = fmaxf(mx.y, __shfl_xor(mx.y, 1));
    mx.z = fmaxf(mx.z, __shfl_xor(mx.z, 1));
    mx.w = fmaxf(mx.w, __shfl_xor(mx.w, 1));

    float ma = half ? mx.z : mx.x;
    float mb = half ? mx.w : mx.y;
    float ca = half ? cv.z : cv.x;
    float cbv= half ? cv.w : cv.y;
    int a0 = n0 + half * 2;
    u32 s0 = __float_as_uint(sqrtf(__fmul_rn(sigm(ma), sigm(ca))));
    u32 s1 = __float_as_uint(sqrtf(__fmul_rn(sigm(mb), sigm(cbv))));
    ulonglong2 kk;
    kk.x = ((u64)s0 << 16) | (u64)(65535 - a0);
    kk.y = ((u64)s1 << 16) | (u64)(65535 - (a0 + 1));
    keyAll2[(((size_t)b * NTOT + n0) >> 1) + half] = kk;

    u32* hb = hist8 + (size_t)(blockIdx.x & (HCOPY - 1)) * (BATCH * NBIN) + (size_t)b * NBIN;
    atomicAdd(&hb[s0 >> 16], 1u);
    atomicAdd(&hb[s1 >> 16], 1u);
}

// ---------------- kernel 2: merge hist copies + threshold bin B1 (fused) ----------------
__global__ __launch_bounds__(1024)
void scanB1_kernel(const u32* __restrict__ hist8, int* __restrict__ selB1) {
    int b = blockIdx.x, tid = threadIdx.x;
    __shared__ u32 ps[1024];
    const u32* h = hist8 + (size_t)b * NBIN;
    u32 loc[16]; u32 sum = 0;
    #pragma unroll
    for (int j = 0; j < 16; ++j) {
        int idx = NBIN - 1 - (tid * 16 + j);
        u32 v = h[idx];
        #pragma unroll
        for (int c = 1; c < HCOPY; ++c) v += h[(size_t)c * (BATCH * NBIN) + idx];
        loc[j] = v; sum += v;
    }
    ps[tid] = sum;
    __syncthreads();
    for (int off = 1; off < 1024; off <<= 1) {
        u32 v = (tid >= off) ? ps[tid - off] : 0u;
        __syncthreads();
        ps[tid] += v;
        __syncthreads();
    }
    u32 incl = ps[tid], excl = incl - sum;
    if (excl < (u32)MAXD && incl >= (u32)MAXD) {
        u32 c = excl;
        #pragma unroll
        for (int j = 0; j < 16; ++j) {
            c += loc[j];
            if (c >= (u32)MAXD) { selB1[b] = NBIN - 1 - (tid * 16 + j); break; }
        }
    }
}

// ---------------- kernel 3: single-pass compact (1 atomic per block) ----------------
// candbuf order is nondeterministic; harmless — rank-sort is order-invariant.
__global__ __launch_bounds__(256)
void compact_kernel(const u64* __restrict__ keyAll, const int* __restrict__ selB1,
                    u32* __restrict__ cntG, u64* __restrict__ candbuf) {
    int n = blockIdx.x * 256 + threadIdx.x;
    int b = blockIdx.y;
    u64 k = 0; bool pred = false;
    if (n < NTOT) {
        k = keyAll[(size_t)b * NTOT + n];
        pred = (int)(k >> 32) >= selB1[b];
    }
    u64 ball = __ballot(pred);
    int lane = threadIdx.x & 63, wid = threadIdx.x >> 6;
    __shared__ u32 wcnt[4];
    __shared__ u32 sbase;
    if (lane == 0) wcnt[wid] = (u32)__popcll(ball);
    __syncthreads();
    if (threadIdx.x == 0)
        sbase = atomicAdd(&cntG[b * 16], wcnt[0] + wcnt[1] + wcnt[2] + wcnt[3]);
    __syncthreads();
    if (pred) {
        u32 wbase = 0;
        #pragma unroll
        for (int i = 0; i < 4; ++i) if (i < wid) wbase += wcnt[i];
        u32 rank = (u32)__popcll(ball & ((1ull << lane) - 1ull));
        u32 dst = sbase + wbase + rank;
        if (dst < CANDCAP) candbuf[(size_t)b * CANDCAP + dst] = k;
    }
}

// ---------------- kernel 4: rank-sort candidates (f64 keys, LDS broadcast) ----------------
__global__ __launch_bounds__(256)
void sort_kernel(const u64* __restrict__ candbuf, const u32* __restrict__ cntG,
                 u64* __restrict__ topkey) {
    int b = blockIdx.y, tid = threadIdx.x;
    int C = min((int)cntG[b * 16], CANDCAP);
    int slice0 = blockIdx.x * 256;
    if (slice0 >= C) return;
    alignas(16) __shared__ double sd[CANDCAP + 2];
    const u64* cb = candbuf + (size_t)b * CANDCAP;
    for (int t2 = tid; t2 < C; t2 += 256) sd[t2] = (double)cb[t2];   // 48-bit keys exact
    if (tid == 0) { sd[C] = -1.0; sd[C + 1] = -1.0; }
    __syncthreads();
    int i = slice0 + tid;
    if (i < C) {
        double ki = sd[i];
        int rank = 0;
        const double2* sd2 = (const double2*)sd;
        int C2 = ((C + 1) & ~1) >> 1;
        for (int j = 0; j < C2; ++j) {
            double2 v2 = sd2[j];
            rank += (v2.x > ki) ? 1 : 0;
            rank += (v2.y > ki) ? 1 : 0;
        }
        if (rank < MAXD) topkey[(size_t)b * KPAD + rank] = cb[i];
    }
}

// ---------------- kernel 5: gather winners (pair-split channels) ----------------
__global__ __launch_bounds__(128, 4)
void gather_kernel(Ptrs ptrs, const u64* __restrict__ topkey,
                   float4* __restrict__ traw, float* __restrict__ tscore,
                   float* __restrict__ tclsf, u32* __restrict__ validwords,
                   u32* __restrict__ maxcG) {
    #pragma clang fp contract(off)
    int b = blockIdx.y;
    int tid = threadIdx.x;
    int half = tid & 1;
    int i = blockIdx.x * 64 + (tid >> 1);
    int active = (i < MAXD);

    float score = 0.f;
    float best = -1.0f; int bi = 0;
    float ra = 0.f, rb2 = 0.f;
    int pos = 0, w = 1, s = 0;
    if (active) {
        u64 key = topkey[(size_t)b * KPAD + i];
        int n = 65535 - (int)(key & 0xFFFFull);
        score = __uint_as_float((u32)(key >> 16));
        int mod = (n >= NMOD) ? 1 : 0;
        int nm = n - mod * NMOD;
        int l, hw;
        level_of(nm, l, pos, w, s, hw);
        const float* clsP = ptrs.p[mod * 15 + l];
        const float* regP = ptrs.p[mod * 15 + 10 + l];
        const float* cbp = clsP + (size_t)b * 20 * hw + pos;
        const float* rbp = regP + (size_t)b * 4 * hw + pos;
        float cl[10];
        int c0 = half * 10;
        #pragma unroll
        for (int c = 0; c < 10; ++c) cl[c] = cbp[(size_t)(c0 + c) * hw];
        ra  = rbp[(size_t)(half * 2) * hw];
        rb2 = rbp[(size_t)(half * 2 + 1) * hw];
        #pragma unroll
        for (int c = 0; c < 10; ++c) {
            float p = sigm(cl[c]);
            if (p > best) { best = p; bi = c0 + c; }
        }
    }
    float po  = __shfl_xor(best, 1);
    int   bio = __shfl_xor(bi, 1);
    float rao = __shfl_xor(ra, 1);
    float rbo = __shfl_xor(rb2, 1);
    if (half == 0) { if (po > best)  { best = po; bi = bio; } }
    else           { if (po >= best) { best = po; bi = bio; } }
    float clsf = active ? (float)(bi + 1) : 0.f;
    float r0 = half ? rao : ra,  r1 = half ? rbo : rb2;
    float r2 = half ? ra  : rao, r3 = half ? rb2 : rbo;

    float4 bx = make_float4(0.f, 0.f, 0.f, 0.f);
    if (active) {
        int xi = pos % w, yi = pos / w;
        float cx = (float)(xi * s + (s >> 1));
        float cy = (float)(yi * s + (s >> 1));
        bx.x = cx - r0; bx.y = cy - r1; bx.z = cx + r2; bx.w = cy + r3;
    }
    int valid = active && (score >= 0.05f) && (half == 0);
    float contrib = valid ? fmaxf(0.0f, fmaxf(fmaxf(bx.x, bx.y), fmaxf(bx.z, bx.w))) : 0.0f;
    float red = contrib;
    #pragma unroll
    for (int off = 32; off > 0; off >>= 1) red = fmaxf(red, __shfl_down(red, off));
    if ((tid & 63) == 0) atomicMax(&maxcG[b * 32], __float_as_uint(red));
    u64 ball = __ballot(valid != 0);
    if ((tid & 63) == 0) {
        u32 word = 0;
        for (int j = 0; j < 32; ++j) word |= (u32)((ball >> (2 * j)) & 1ull) << j;
        validwords[b * 32 + blockIdx.x * 2 + (tid >> 6)] = word;
    }
    if (half == 0) {
        size_t oo = (size_t)b * KPAD + i;
        traw[oo] = bx; tscore[oo] = score; tclsf[oo] = clsf;
    }
}

// ---------------- kernel 6: IoU>0.6 bitmask, upper-triangle units ----------------
#define SW(t) ((((t) & 31) << 3) | ((t) >> 5))
__global__ __launch_bounds__(64)
void mask_kernel(const float4* __restrict__ traw, const float* __restrict__ tclsf,
                 const u32* __restrict__ maxcG, u32* __restrict__ maskG) {
    #pragma clang fp contract(off)
    int u = blockIdx.x, b = blockIdx.y, tid = threadIdx.x;
    int g, wg;
    if (u < 128)      { g = u >> 2;                 wg = u & 3; }
    else if (u < 224) { int i2 = u - 128; g = 32 + i2 / 3;      wg = 1 + i2 % 3; }
    else if (u < 288) { int i2 = u - 224; g = 64 + (i2 >> 1);   wg = 2 + (i2 & 1); }
    else              { g = 96 + (u - 288);         wg = 3; }
    int i0 = g * 8, j0 = wg * 256;
    float m1 = __uint_as_float(maxcG[b * 32]) + 1.0f;

    __shared__ float cx1[256], cy1[256], cx2[256], cy2[256], ca[256];
    for (int t = tid; t < 256; t += 64) {
        float4 f = traw[(size_t)b * KPAD + j0 + t];
        float o = __fmul_rn(tclsf[(size_t)b * KPAD + j0 + t], m1);
        float ox1 = __fadd_rn(f.x, o), oy1 = __fadd_rn(f.y, o);
        float ox2 = __fadd_rn(f.z, o), oy2 = __fadd_rn(f.w, o);
        float dw = ox2 - ox1 + 1.0f;
        float dh = oy2 - oy1 + 1.0f;
        int ts = SW(t);
        cx1[ts] = ox1; cy1[ts] = oy1; cx2[ts] = ox2; cy2[ts] = oy2;
        ca[ts] = __fmul_rn(dw, dh);
    }
    __syncthreads();

    int ir = tid >> 3, wr = tid & 7;
    int i = i0 + ir;
    float4 fi = traw[(size_t)b * KPAD + i];
    float oi = __fmul_rn(tclsf[(size_t)b * KPAD + i], m1);
    float ix1 = __fadd_rn(fi.x, oi), iy1 = __fadd_rn(fi.y, oi);
    float ix2 = __fadd_rn(fi.z, oi), iy2 = __fadd_rn(fi.w, oi);
    float dwi = ix2 - ix1 + 1.0f, dhi = iy2 - iy1 + 1.0f;
    float ai = __fmul_rn(dwi, dhi);
    u32 bits = 0;
    int jb = wr * 32;
    for (int jj = 0; jj < 32; ++jj) {
        int js = SW(jb + jj);
        float iw = fminf(ix2, cx2[js]) - fmaxf(ix1, cx1[js]) + 1.0f;
        iw = fmaxf(iw, 0.0f);
        float ih = fminf(iy2, cy2[js]) - fmaxf(iy1, cy1[js]) + 1.0f;
        ih = fmaxf(ih, 0.0f);
        float inter = iw * ih;
        float denom = (ai + ca[js]) - inter;
        float iou = inter / denom;
        bits |= (iou > 0.6f) ? (1u << jj) : 0u;
    }
    maskG[((size_t)b * KPAD + i) * 32 + wg * 8 + wr] = bits;
}

// ---------------- kernel 7: greedy scan (1 wave/batch, depth-16 prefetch) + outputs ----------------
__global__ __launch_bounds__(64)
void scan_out_kernel(const u32* __restrict__ maskG, const u32* __restrict__ validbits,
                     const float4* __restrict__ traw, const float* __restrict__ tscore,
                     const float* __restrict__ tclsf, float* __restrict__ out) {
    int b = blockIdx.x, lane = threadIdx.x;
    int lw = lane & 31;
    const u32* mrow = maskG + (size_t)b * KPAD * 32;
    u32 vreg = (lane < 32) ? validbits[b * 32 + lane] : 0u;
    u32 removed = 0u, keepw = 0u;
    u32 mA[8], mB[8];
    #pragma unroll
    for (int d = 0; d < 8; ++d) {
        mA[d] = mrow[(size_t)d * 32 + lw];
        mB[d] = mrow[(size_t)(d + 8) * 32 + lw];
    }
    auto step8 = [&](int base, u32* ms) {
        #pragma unroll
        for (int d = 0; d < 8; ++d) {
            int i = base + d;
            int wi = i >> 5, bi2 = i & 31;
            u32 rw = (u32)__builtin_amdgcn_readlane((int)removed, wi);
            u32 vw = (u32)__builtin_amdgcn_readlane((int)vreg, wi);
            u32 k = ((vw >> bi2) & 1u) & (~(rw >> bi2) & 1u);
            if (k) removed |= ms[d];
            if (lane == wi) keepw |= (k << bi2);
            ms[d] = mrow[(size_t)(i + 16) * 32 + lw];
        }
    };
    for (int t = 0; t < 62; ++t) { step8(t * 16, mA); step8(t * 16 + 8, mB); }
    step8(992, mA);

    __shared__ u32 keeps[32];
    if (lane < 32) keeps[lane] = keepw;
    __syncthreads();
    const int BQ = BATCH * MAXD;
    for (int s2 = lane; s2 < MAXD; s2 += 64) {
        u32 kf = (keeps[s2 >> 5] >> (s2 & 31)) & 1u;
        size_t oo = (size_t)b * KPAD + s2;
        float score = tscore[oo];
        float clsf = tclsf[oo];
        float4 bx = traw[oo];
        float x1 = fminf(fmaxf(bx.x, 0.f), 1279.f);
        float y1 = fminf(fmaxf(bx.y, 0.f), 1023.f);
        float x2 = fminf(fmaxf(bx.z, 0.f), 1279.f);
        float y2 = fminf(fmaxf(bx.w, 0.f), 1023.f);
        int base = b * MAXD + s2;
        out[base] = kf ? score : 0.0f;
        out[BQ + base] = kf ? clsf : 0.0f;
        float* ob = out + 2 * BQ + (size_t)base * 4;
        ob[0] = kf ? x1 : 0.f; ob[1] = kf ? y1 : 0.f;
        ob[2] = kf ? x2 : 0.f; ob[3] = kf ? y2 : 0.f;
        out[6 * BQ + base] = kf ? 1.0f : 0.0f;
    }
}

// ---------------- launch ----------------
extern "C" void kernel_launch(void* const* d_in, const int* in_sizes, int n_in,
                              void* d_out, int out_size, void* d_ws, size_t ws_size,
                              hipStream_t stream) {
    Ptrs ptrs;
    for (int i = 0; i < 30; ++i) ptrs.p[i] = (const float*)d_in[i];

    char* ws = (char*)d_ws;
    u64*        keyAll    = (u64*)       (ws + OFF_KEY);
    ulonglong2* keyAll2   = (ulonglong2*)(ws + OFF_KEY);
    u64*        topkey    = (u64*)       (ws + OFF_TOPK);
    u64*        candbuf   = (u64*)       (ws + OFF_CAND);
    float4*     traw      = (float4*)    (ws + OFF_TRAW);
    float*      tscore    = (float*)     (ws + OFF_TSCORE);
    float*      tclsf     = (float*)     (ws + OFF_TCLSF);
    int*        selB1     = (int*)       (ws + OFF_SELB);
    u32*        cntG      = (u32*)       (ws + OFF_CNTG);
    u32*        maxcG     = (u32*)       (ws + OFF_MAXC);
    u32*        validbits = (u32*)       (ws + OFF_VALID);
    u32*        hist8     = (u32*)       (ws + OFF_HIST8);
    u32*        maskG     = (u32*)       (ws + OFF_MASK);
    float*      out       = (float*)d_out;

    hipMemsetAsync(ws + OFF_CNTG, 0, SZ_ZERO, stream);

    decode_kernel<<<dim3((NTOT / 2 + 255) / 256, BATCH), 256, 0, stream>>>(ptrs, keyAll2, hist8);
    scanB1_kernel<<<BATCH, 1024, 0, stream>>>(hist8, selB1);
    compact_kernel<<<dim3(NB, BATCH), 256, 0, stream>>>(keyAll, selB1, cntG, candbuf);
    sort_kernel<<<dim3(CANDCAP / 256, BATCH), 256, 0, stream>>>(candbuf, cntG, topkey);
    gather_kernel<<<dim3(16, BATCH), 128, 0, stream>>>(ptrs, topkey, traw, tscore, tclsf,
                                                       validbits, maxcG);
    mask_kernel<<<dim3(320, BATCH), 64, 0, stream>>>(traw, tclsf, maxcG, maskG);
    scan_out_kernel<<<BATCH, 64, 0, stream>>>(maskG, validbits, traw, tscore, tclsf, out);
}

// Round 7
// 284.299 us; speedup vs baseline: 1.6628x; 1.0609x over previous
//
#include <hip/hip_runtime.h>
#include <hip/hip_bf16.h>

typedef unsigned long long u64;
typedef unsigned int u32;

#define NTOT    54560   // anchors per batch (r + i)
#define NMOD    27280   // anchors per modality
#define BATCH   16
#define KPAD    1024
#define MAXD    1000
#define NBIN    16384   // score-bits >> 16
#define CANDCAP 6144    // LDS candidate cap (doubles, 48KB)

struct Ptrs { const float* p[30]; };

// ---------------- workspace layout (16B aligned) ----------------
constexpr size_t SZ_KEY   = (size_t)BATCH * NTOT * 8;        // 6.98 MB
constexpr size_t SZ_TOPK  = (size_t)BATCH * KPAD * 8;
constexpr size_t SZ_TRAW  = (size_t)BATCH * KPAD * 16;
constexpr size_t SZ_T1    = (size_t)BATCH * KPAD * 4;
constexpr size_t SZ_MAXC  = (size_t)BATCH * 32 * 4;
constexpr size_t SZ_VALID = (size_t)BATCH * 32 * 4;
constexpr size_t SZ_MASK  = (size_t)BATCH * KPAD * 32 * 4;   // 2 MB

constexpr size_t OFF_KEY    = 0;
constexpr size_t OFF_TOPK   = OFF_KEY   + SZ_KEY;
constexpr size_t OFF_TRAW   = OFF_TOPK  + SZ_TOPK;
constexpr size_t OFF_TSCORE = OFF_TRAW  + SZ_TRAW;
constexpr size_t OFF_TCLSF  = OFF_TSCORE+ SZ_T1;
constexpr size_t OFF_MAXC   = OFF_TCLSF + SZ_T1;
constexpr size_t OFF_VALID  = OFF_MAXC  + SZ_MAXC;
constexpr size_t OFF_MASK   = OFF_VALID + SZ_VALID;

__device__ inline void level_of(int nm, int& l, int& pos, int& w, int& s, int& hw) {
    if (nm < 20480)      { l = 0; pos = nm;         w = 160; s = 8;   hw = 20480; }
    else if (nm < 25600) { l = 1; pos = nm - 20480; w = 80;  s = 16;  hw = 5120; }
    else if (nm < 26880) { l = 2; pos = nm - 25600; w = 40;  s = 32;  hw = 1280; }
    else if (nm < 27200) { l = 3; pos = nm - 26880; w = 20;  s = 64;  hw = 320; }
    else                 { l = 4; pos = nm - 27200; w = 10;  s = 128; hw = 80; }
}

__device__ inline float sigm(float x) { return 1.0f / (1.0f + expf(-x)); }

// ---------------- kernel 1: decode scores -> keys (no atomics) ----------------
// quad-split: 4 lanes share one float4 anchor-group; 5 channels per lane,
// combined via shfl_xor(1),(2). waves_per_eu max=4 -> scheduler RP target 128
// VGPR -> all 6 loads batch into one vmcnt round-trip.
__global__ __launch_bounds__(256) __attribute__((amdgpu_waves_per_eu(2, 4)))
void decode_kernel(Ptrs ptrs, u64* __restrict__ keyAll) {
    int t = blockIdx.x * 256 + threadIdx.x;
    int b = blockIdx.y;
    if (t >= NTOT) return;
    int q = t & 3;
    int n0 = t & ~3;
    int mod = (n0 >= NMOD) ? 1 : 0;
    int nm = n0 - mod * NMOD;
    int l, pos, w, s, hw;
    level_of(nm, l, pos, w, s, hw);
    (void)w; (void)s;
    const float* clsP = ptrs.p[mod * 15 + l];
    const float* cntP = ptrs.p[mod * 15 + 5 + l];
    const float4* cb = (const float4*)(clsP + (size_t)b * 20 * hw + pos);
    int hw4 = hw >> 2;
    int c0 = q * 5;
    float4 v[5];
    #pragma unroll
    for (int c = 0; c < 5; ++c) v[c] = cb[(size_t)(c0 + c) * hw4];
    float4 cv = *(const float4*)(cntP + (size_t)b * hw + pos);

    float4 mx = v[0];
    #pragma unroll
    for (int c = 1; c < 5; ++c) {
        mx.x = fmaxf(mx.x, v[c].x); mx.y = fmaxf(mx.y, v[c].y);
        mx.z = fmaxf(mx.z, v[c].z); mx.w = fmaxf(mx.w, v[c].w);
    }
    mx.x = fmaxf(mx.x, __shfl_xor(mx.x, 1));
    mx.y = fmaxf(mx.y, __shfl_xor(mx.y, 1));
    mx.z = fmaxf(mx.z, __shfl_xor(mx.z, 1));
    mx.w = fmaxf(mx.w, __shfl_xor(mx.w, 1));
    mx.x = fmaxf(mx.x, __shfl_xor(mx.x, 2));
    mx.y = fmaxf(mx.y, __shfl_xor(mx.y, 2));
    mx.z = fmaxf(mx.z, __shfl_xor(mx.z, 2));
    mx.w = fmaxf(mx.w, __shfl_xor(mx.w, 2));

    float ma = (q & 1) ? ((q & 2) ? mx.w : mx.y) : ((q & 2) ? mx.z : mx.x);
    float ca = (q & 1) ? ((q & 2) ? cv.w : cv.y) : ((q & 2) ? cv.z : cv.x);
    // max-before-sigmoid: bitwise equal to sigmoid-then-max (monotone)
    u32 sb = __float_as_uint(sqrtf(__fmul_rn(sigm(ma), sigm(ca))));
    keyAll[(size_t)b * NTOT + t] = ((u64)sb << 16) | (u64)(65535 - t);
}

// ---------------- kernel 2: fused select (LDS hist + B1 + compact + rank-sort) ----------------
__global__ __launch_bounds__(1024)
void select_kernel(const u64* __restrict__ keyAll, u64* __restrict__ topkey,
                   u32* __restrict__ maxcG) {
    int b = blockIdx.x, tid = threadIdx.x;
    int lane = tid & 63, wid = tid >> 6;
    __shared__ u32 shist[NBIN];          // 64KB; reused as double sk[] after B1
    __shared__ u32 warep[16];
    __shared__ int sB1;
    __shared__ u32 scnt;
    double* sd = (double*)shist;

    if (tid == 0) { maxcG[b * 32] = 0u; scnt = 0u; }
    #pragma unroll
    for (int j = 0; j < NBIN / 1024; ++j) shist[tid + j * 1024] = 0u;
    __syncthreads();

    const u64* keys = keyAll + (size_t)b * NTOT;
    const u64 SENT = ~0ull;
    // phase 1: LDS histogram (8-deep load batches)
    for (int n0 = 0; n0 < NTOT; n0 += 8192) {
        u64 kk[8];
        #pragma unroll
        for (int r = 0; r < 8; ++r) {
            int idx = n0 + r * 1024 + tid;
            kk[r] = (idx < NTOT) ? keys[idx] : SENT;
        }
        #pragma unroll
        for (int r = 0; r < 8; ++r)
            if (kk[r] != SENT) atomicAdd(&shist[(u32)(kk[r] >> 32)], 1u);
    }
    __syncthreads();

    // phase 2: reversed cumulative scan -> B1 (wave-shuffle scan, 2 barriers)
    u32 loc[16]; u32 sum = 0;
    #pragma unroll
    for (int j = 0; j < 16; ++j) { loc[j] = shist[NBIN - 1 - (tid * 16 + j)]; sum += loc[j]; }
    u32 v = sum;
    #pragma unroll
    for (int off = 1; off < 64; off <<= 1) {
        u32 t2 = (u32)__shfl_up((int)v, off);
        if (lane >= off) v += t2;
    }
    if (lane == 63) warep[wid] = v;
    __syncthreads();
    if (tid < 16) {
        u32 p = warep[tid];
        #pragma unroll
        for (int off = 1; off < 16; off <<= 1) {
            u32 t2 = (u32)__shfl_up((int)p, off);
            if (tid >= off) p += t2;
        }
        warep[tid] = p;
    }
    __syncthreads();
    u32 incl = v + (wid ? warep[wid - 1] : 0u);
    u32 excl = incl - sum;
    if (excl < (u32)MAXD && incl >= (u32)MAXD) {
        u32 c = excl;
        #pragma unroll
        for (int j = 0; j < 16; ++j) {
            c += loc[j];
            if (c >= (u32)MAXD) { sB1 = NBIN - 1 - (tid * 16 + j); break; }
        }
    }
    __syncthreads();
    int B1 = sB1;

    // phase 3: compact candidates (bin >= B1) into LDS as exact doubles
    for (int n0 = 0; n0 < NTOT; n0 += 8192) {
        u64 kk[8];
        #pragma unroll
        for (int r = 0; r < 8; ++r) {
            int idx = n0 + r * 1024 + tid;
            kk[r] = (idx < NTOT) ? keys[idx] : 0ull;   // real keys never 0 (low16 >= 10976)
        }
        #pragma unroll
        for (int r = 0; r < 8; ++r) {
            if (kk[r] != 0ull && (int)(kk[r] >> 32) >= B1) {
                u32 p = atomicAdd(&scnt, 1u);
                if (p < CANDCAP - 2) sd[p] = (double)kk[r];   // 48-bit keys exact
            }
        }
    }
    __syncthreads();
    int C = min((int)scnt, CANDCAP - 2);
    if (tid == 0) { sd[C] = -1.0; sd[C + 1] = -1.0; }
    __syncthreads();

    // phase 4: rank-sort (distinct keys -> bijection onto ranks)
    for (int i = tid; i < C; i += 1024) {
        double ki = sd[i];
        int rank = 0;
        const double2* sd2 = (const double2*)sd;
        int C2 = (C + 1) >> 1;
        for (int j = 0; j < C2; ++j) {
            double2 v2 = sd2[j];
            rank += (v2.x > ki) ? 1 : 0;
            rank += (v2.y > ki) ? 1 : 0;
        }
        if (rank < MAXD) topkey[(size_t)b * KPAD + rank] = (u64)ki;
    }
}

// ---------------- kernel 3: gather winners (pair-split channels) ----------------
__global__ __launch_bounds__(128) __attribute__((amdgpu_waves_per_eu(2, 4)))
void gather_kernel(Ptrs ptrs, const u64* __restrict__ topkey,
                   float4* __restrict__ traw, float* __restrict__ tscore,
                   float* __restrict__ tclsf, u32* __restrict__ validwords,
                   u32* __restrict__ maxcG) {
    #pragma clang fp contract(off)
    int b = blockIdx.y;
    int tid = threadIdx.x;
    int half = tid & 1;
    int i = blockIdx.x * 64 + (tid >> 1);
    int active = (i < MAXD);

    float score = 0.f;
    float best = -1.0f; int bi = 0;
    float ra = 0.f, rb2 = 0.f;
    int pos = 0, w = 1, s = 0;
    if (active) {
        u64 key = topkey[(size_t)b * KPAD + i];
        int n = 65535 - (int)(key & 0xFFFFull);
        score = __uint_as_float((u32)(key >> 16));
        int mod = (n >= NMOD) ? 1 : 0;
        int nm = n - mod * NMOD;
        int l, hw;
        level_of(nm, l, pos, w, s, hw);
        const float* clsP = ptrs.p[mod * 15 + l];
        const float* regP = ptrs.p[mod * 15 + 10 + l];
        const float* cbp = clsP + (size_t)b * 20 * hw + pos;
        const float* rbp = regP + (size_t)b * 4 * hw + pos;
        float cl[10];
        int c0 = half * 10;
        #pragma unroll
        for (int c = 0; c < 10; ++c) cl[c] = cbp[(size_t)(c0 + c) * hw];
        ra  = rbp[(size_t)(half * 2) * hw];
        rb2 = rbp[(size_t)(half * 2 + 1) * hw];
        #pragma unroll
        for (int c = 0; c < 10; ++c) {
            float p = sigm(cl[c]);
            if (p > best) { best = p; bi = c0 + c; }
        }
    }
    float po  = __shfl_xor(best, 1);
    int   bio = __shfl_xor(bi, 1);
    float rao = __shfl_xor(ra, 1);
    float rbo = __shfl_xor(rb2, 1);
    if (half == 0) { if (po > best)  { best = po; bi = bio; } }
    else           { if (po >= best) { best = po; bi = bio; } }
    float clsf = active ? (float)(bi + 1) : 0.f;
    float r0 = half ? rao : ra,  r1 = half ? rbo : rb2;
    float r2 = half ? ra  : rao, r3 = half ? rb2 : rbo;

    float4 bx = make_float4(0.f, 0.f, 0.f, 0.f);
    if (active) {
        int xi = pos % w, yi = pos / w;
        float cx = (float)(xi * s + (s >> 1));
        float cy = (float)(yi * s + (s >> 1));
        bx.x = cx - r0; bx.y = cy - r1; bx.z = cx + r2; bx.w = cy + r3;
    }
    int valid = active && (score >= 0.05f) && (half == 0);
    float contrib = valid ? fmaxf(0.0f, fmaxf(fmaxf(bx.x, bx.y), fmaxf(bx.z, bx.w))) : 0.0f;
    float red = contrib;
    #pragma unroll
    for (int off = 32; off > 0; off >>= 1) red = fmaxf(red, __shfl_down(red, off));
    if ((tid & 63) == 0) atomicMax(&maxcG[b * 32], __float_as_uint(red));
    u64 ball = __ballot(valid != 0);
    if ((tid & 63) == 0) {
        u32 word = 0;
        for (int j = 0; j < 32; ++j) word |= (u32)((ball >> (2 * j)) & 1ull) << j;
        validwords[b * 32 + blockIdx.x * 2 + (tid >> 6)] = word;
    }
    if (half == 0) {
        size_t oo = (size_t)b * KPAD + i;
        traw[oo] = bx; tscore[oo] = score; tclsf[oo] = clsf;   // zeros for i >= MAXD
    }
}

// ---------------- kernel 4: IoU>0.6 bitmask, upper-triangle units ----------------
// Unwritten strictly-lower words stay poisoned; scan only consumes bit j at
// step j, and garbage ORs only touch already-processed columns -> harmless.
#define SW(t) ((((t) & 31) << 3) | ((t) >> 5))
__global__ __launch_bounds__(64)
void mask_kernel(const float4* __restrict__ traw, const float* __restrict__ tclsf,
                 const u32* __restrict__ maxcG, u32* __restrict__ maskG) {
    #pragma clang fp contract(off)
    int u = blockIdx.x, b = blockIdx.y, tid = threadIdx.x;
    int g, wg;
    if (u < 128)      { g = u >> 2;                 wg = u & 3; }
    else if (u < 224) { int i2 = u - 128; g = 32 + i2 / 3;      wg = 1 + i2 % 3; }
    else if (u < 288) { int i2 = u - 224; g = 64 + (i2 >> 1);   wg = 2 + (i2 & 1); }
    else              { g = 96 + (u - 288);         wg = 3; }
    int i0 = g * 8, j0 = wg * 256;
    float m1 = __uint_as_float(maxcG[b * 32]) + 1.0f;

    __shared__ float cx1[256], cy1[256], cx2[256], cy2[256], ca[256];
    for (int t = tid; t < 256; t += 64) {
        float4 f = traw[(size_t)b * KPAD + j0 + t];
        float o = __fmul_rn(tclsf[(size_t)b * KPAD + j0 + t], m1);
        float ox1 = __fadd_rn(f.x, o), oy1 = __fadd_rn(f.y, o);
        float ox2 = __fadd_rn(f.z, o), oy2 = __fadd_rn(f.w, o);
        float dw = ox2 - ox1 + 1.0f;
        float dh = oy2 - oy1 + 1.0f;
        int ts = SW(t);
        cx1[ts] = ox1; cy1[ts] = oy1; cx2[ts] = ox2; cy2[ts] = oy2;
        ca[ts] = __fmul_rn(dw, dh);
    }
    __syncthreads();

    int ir = tid >> 3, wr = tid & 7;
    int i = i0 + ir;
    float4 fi = traw[(size_t)b * KPAD + i];
    float oi = __fmul_rn(tclsf[(size_t)b * KPAD + i], m1);
    float ix1 = __fadd_rn(fi.x, oi), iy1 = __fadd_rn(fi.y, oi);
    float ix2 = __fadd_rn(fi.z, oi), iy2 = __fadd_rn(fi.w, oi);
    float dwi = ix2 - ix1 + 1.0f, dhi = iy2 - iy1 + 1.0f;
    float ai = __fmul_rn(dwi, dhi);
    u32 bits = 0;
    int jb = wr * 32;
    for (int jj = 0; jj < 32; ++jj) {
        int js = SW(jb + jj);
        float iw = fminf(ix2, cx2[js]) - fmaxf(ix1, cx1[js]) + 1.0f;
        iw = fmaxf(iw, 0.0f);
        float ih = fminf(iy2, cy2[js]) - fmaxf(iy1, cy1[js]) + 1.0f;
        ih = fmaxf(ih, 0.0f);
        float inter = iw * ih;
        float denom = (ai + ca[js]) - inter;
        float iou = inter / denom;
        bits |= (iou > 0.6f) ? (1u << jj) : 0u;
    }
    maskG[((size_t)b * KPAD + i) * 32 + wg * 8 + wr] = bits;
}

// ---------------- kernel 5: greedy scan (1 wave/batch, depth-16 prefetch) + outputs ----------------
__global__ __launch_bounds__(64)
void scan_out_kernel(const u32* __restrict__ maskG, const u32* __restrict__ validbits,
                     const float4* __restrict__ traw, const float* __restrict__ tscore,
                     const float* __restrict__ tclsf, float* __restrict__ out) {
    int b = blockIdx.x, lane = threadIdx.x;
    int lw = lane & 31;
    const u32* mrow = maskG + (size_t)b * KPAD * 32;
    u32 vreg = (lane < 32) ? validbits[b * 32 + lane] : 0u;
    u32 removed = 0u, keepw = 0u;
    u32 mA[8], mB[8];
    #pragma unroll
    for (int d = 0; d < 8; ++d) {
        mA[d] = mrow[(size_t)d * 32 + lw];
        mB[d] = mrow[(size_t)(d + 8) * 32 + lw];
    }
    auto step8 = [&](int base, u32* ms) {
        #pragma unroll
        for (int d = 0; d < 8; ++d) {
            int i = base + d;
            int wi = i >> 5, bi2 = i & 31;
            u32 rw = (u32)__builtin_amdgcn_readlane((int)removed, wi);
            u32 vw = (u32)__builtin_amdgcn_readlane((int)vreg, wi);
            u32 k = ((vw >> bi2) & 1u) & (~(rw >> bi2) & 1u);
            if (k) removed |= ms[d];
            if (lane == wi) keepw |= (k << bi2);
            ms[d] = mrow[(size_t)(i + 16) * 32 + lw];
        }
    };
    for (int t = 0; t < 62; ++t) { step8(t * 16, mA); step8(t * 16 + 8, mB); }
    step8(992, mA);

    __shared__ u32 keeps[32];
    if (lane < 32) keeps[lane] = keepw;
    __syncthreads();
    const int BQ = BATCH * MAXD;
    for (int s2 = lane; s2 < MAXD; s2 += 64) {
        u32 kf = (keeps[s2 >> 5] >> (s2 & 31)) & 1u;
        size_t oo = (size_t)b * KPAD + s2;
        float score = tscore[oo];
        float clsf = tclsf[oo];
        float4 bx = traw[oo];
        float x1 = fminf(fmaxf(bx.x, 0.f), 1279.f);
        float y1 = fminf(fmaxf(bx.y, 0.f), 1023.f);
        float x2 = fminf(fmaxf(bx.z, 0.f), 1279.f);
        float y2 = fminf(fmaxf(bx.w, 0.f), 1023.f);
        int base = b * MAXD + s2;
        out[base] = kf ? score : 0.0f;
        out[BQ + base] = kf ? clsf : 0.0f;
        float* ob = out + 2 * BQ + (size_t)base * 4;
        ob[0] = kf ? x1 : 0.f; ob[1] = kf ? y1 : 0.f;
        ob[2] = kf ? x2 : 0.f; ob[3] = kf ? y2 : 0.f;
        out[6 * BQ + base] = kf ? 1.0f : 0.0f;
    }
}

// ---------------- launch (5 nodes, no memsets) ----------------
extern "C" void kernel_launch(void* const* d_in, const int* in_sizes, int n_in,
                              void* d_out, int out_size, void* d_ws, size_t ws_size,
                              hipStream_t stream) {
    Ptrs ptrs;
    for (int i = 0; i < 30; ++i) ptrs.p[i] = (const float*)d_in[i];

    char* ws = (char*)d_ws;
    u64*    keyAll    = (u64*)   (ws + OFF_KEY);
    u64*    topkey    = (u64*)   (ws + OFF_TOPK);
    float4* traw      = (float4*)(ws + OFF_TRAW);
    float*  tscore    = (float*) (ws + OFF_TSCORE);
    float*  tclsf     = (float*) (ws + OFF_TCLSF);
    u32*    maxcG     = (u32*)   (ws + OFF_MAXC);
    u32*    validbits = (u32*)   (ws + OFF_VALID);
    u32*    maskG     = (u32*)   (ws + OFF_MASK);
    float*  out       = (float*)d_out;

    decode_kernel<<<dim3((NTOT + 255) / 256, BATCH), 256, 0, stream>>>(ptrs, keyAll);
    select_kernel<<<BATCH, 1024, 0, stream>>>(keyAll, topkey, maxcG);
    gather_kernel<<<dim3(16, BATCH), 128, 0, stream>>>(ptrs, topkey, traw, tscore, tclsf,
                                                       validbits, maxcG);
    mask_kernel<<<dim3(320, BATCH), 64, 0, stream>>>(traw, tclsf, maxcG, maskG);
    scan_out_kernel<<<BATCH, 64, 0, stream>>>(maskG, validbits, traw, tscore, tclsf, out);
}

// Round 8
// 277.616 us; speedup vs baseline: 1.7028x; 1.0241x over previous
//
#include <hip/hip_runtime.h>
#include <hip/hip_bf16.h>

typedef unsigned long long u64;
typedef unsigned int u32;

#define NTOT    54560   // anchors per batch (r + i)
#define NMOD    27280   // anchors per modality
#define BATCH   16
#define KPAD    1024
#define MAXD    1000
#define NBIN    16384   // score-bits >> 16
#define CANDCAP 6144    // LDS candidate cap (doubles, 48KB)
#define NLDSPOS 25600   // positions per modality covered by the LDS decode path

struct Ptrs { const float* p[30]; };

// ---------------- workspace layout (16B aligned) ----------------
constexpr size_t SZ_KEY   = (size_t)BATCH * NTOT * 8;        // 6.98 MB
constexpr size_t SZ_TOPK  = (size_t)BATCH * KPAD * 8;
constexpr size_t SZ_TRAW  = (size_t)BATCH * KPAD * 16;
constexpr size_t SZ_T1    = (size_t)BATCH * KPAD * 4;
constexpr size_t SZ_MAXC  = (size_t)BATCH * 32 * 4;
constexpr size_t SZ_VALID = (size_t)BATCH * 32 * 4;
constexpr size_t SZ_MASK  = (size_t)BATCH * KPAD * 32 * 4;   // 2 MB

constexpr size_t OFF_KEY    = 0;
constexpr size_t OFF_TOPK   = OFF_KEY   + SZ_KEY;
constexpr size_t OFF_TRAW   = OFF_TOPK  + SZ_TOPK;
constexpr size_t OFF_TSCORE = OFF_TRAW  + SZ_TRAW;
constexpr size_t OFF_TCLSF  = OFF_TSCORE+ SZ_T1;
constexpr size_t OFF_MAXC   = OFF_TCLSF + SZ_T1;
constexpr size_t OFF_VALID  = OFF_MAXC  + SZ_MAXC;
constexpr size_t OFF_MASK   = OFF_VALID + SZ_VALID;

__device__ inline void level_of(int nm, int& l, int& pos, int& w, int& s, int& hw) {
    if (nm < 20480)      { l = 0; pos = nm;         w = 160; s = 8;   hw = 20480; }
    else if (nm < 25600) { l = 1; pos = nm - 20480; w = 80;  s = 16;  hw = 5120; }
    else if (nm < 26880) { l = 2; pos = nm - 25600; w = 40;  s = 32;  hw = 1280; }
    else if (nm < 27200) { l = 3; pos = nm - 26880; w = 20;  s = 64;  hw = 320; }
    else                 { l = 4; pos = nm - 27200; w = 10;  s = 128; hw = 80; }
}

__device__ inline float sigm(float x) { return 1.0f / (1.0f + expf(-x)); }

// async global->LDS DMA, 16B per lane; LDS dest = uniform base + lane*16
__device__ inline void ld_lds16(const float* g, float* l) {
    __builtin_amdgcn_global_load_lds(
        (const __attribute__((address_space(1))) void*)g,
        (__attribute__((address_space(3))) void*)l, 16, 0, 0);
}

// ---------------- kernel 1a: decode levels 0-1 via global_load_lds staging ----------------
// block = one 1024-anchor chunk of one (modality, level). 21 channels staged
// async into 84KB LDS (no VGPR round-trip, deep DMA queue), then per-thread
// max over 20 ds_read_b128. max-before-sigmoid == sigmoid-then-max (monotone).
__global__ __launch_bounds__(256)
void decode_lds_kernel(Ptrs ptrs, u64* __restrict__ keyAll) {
    __shared__ float lds[21 * 1024];    // 84KB
    int cc = blockIdx.x;                // 0..49
    int b = blockIdx.y;
    int mod = cc / 25, c = cc % 25;
    int l     = (c < 20) ? 0 : 1;
    int hw    = (c < 20) ? 20480 : 5120;
    int pos0  = (c < 20) ? c * 1024 : (c - 20) * 1024;
    int nmb   = (l == 0) ? pos0 : 20480 + pos0;
    const float* clsP = ptrs.p[mod * 15 + l];
    const float* cntP = ptrs.p[mod * 15 + 5 + l];
    int wave = threadIdx.x >> 6, lane = threadIdx.x & 63;

    const float* cbase = clsP + (size_t)b * 20 * hw + pos0 + wave * 256 + lane * 4;
    float* dbase = lds + wave * 256;
    #pragma unroll
    for (int ch = 0; ch < 20; ++ch)
        ld_lds16(cbase + (size_t)ch * hw, dbase + ch * 1024);
    ld_lds16(cntP + (size_t)b * hw + pos0 + wave * 256 + lane * 4, dbase + 20 * 1024);
    __syncthreads();   // compiler drains vmcnt before s_barrier

    int t = threadIdx.x;
    const float4* l4 = (const float4*)lds;
    float4 mx = l4[t];
    #pragma unroll
    for (int ch = 1; ch < 20; ++ch) {
        float4 v = l4[ch * 256 + t];
        mx.x = fmaxf(mx.x, v.x); mx.y = fmaxf(mx.y, v.y);
        mx.z = fmaxf(mx.z, v.z); mx.w = fmaxf(mx.w, v.w);
    }
    float4 cv = l4[20 * 256 + t];

    int n = mod * NMOD + nmb + t * 4;
    u32 s0 = __float_as_uint(sqrtf(__fmul_rn(sigm(mx.x), sigm(cv.x))));
    u32 s1 = __float_as_uint(sqrtf(__fmul_rn(sigm(mx.y), sigm(cv.y))));
    u32 s2 = __float_as_uint(sqrtf(__fmul_rn(sigm(mx.z), sigm(cv.z))));
    u32 s3 = __float_as_uint(sqrtf(__fmul_rn(sigm(mx.w), sigm(cv.w))));
    ulonglong2* ka2 = (ulonglong2*)(keyAll + (size_t)b * NTOT + n);
    ulonglong2 k01, k23;
    k01.x = ((u64)s0 << 16) | (u64)(65535 - n);
    k01.y = ((u64)s1 << 16) | (u64)(65535 - (n + 1));
    k23.x = ((u64)s2 << 16) | (u64)(65535 - (n + 2));
    k23.y = ((u64)s3 << 16) | (u64)(65535 - (n + 3));
    ka2[0] = k01; ka2[1] = k23;
}

// ---------------- kernel 1b: decode tail (levels 2-4), quad-split ----------------
__global__ __launch_bounds__(256)
void decode_tail_kernel(Ptrs ptrs, u64* __restrict__ keyAll) {
    int t = blockIdx.x * 256 + threadIdx.x;   // 0..3359
    int b = blockIdx.y;
    if (t >= 3360) return;
    int mod = t / 1680;
    int tm = t % 1680;
    int q = t & 3;
    int nm = 25600 + (tm & ~3);               // quad base (1680 % 4 == 0)
    int l, pos, w, s, hw;
    level_of(nm, l, pos, w, s, hw);
    (void)w; (void)s;
    const float* clsP = ptrs.p[mod * 15 + l];
    const float* cntP = ptrs.p[mod * 15 + 5 + l];
    const float4* cb = (const float4*)(clsP + (size_t)b * 20 * hw + pos);
    int hw4 = hw >> 2;
    int c0 = q * 5;
    float4 v[5];
    #pragma unroll
    for (int c = 0; c < 5; ++c) v[c] = cb[(size_t)(c0 + c) * hw4];
    float4 cv = *(const float4*)(cntP + (size_t)b * hw + pos);

    float4 mx = v[0];
    #pragma unroll
    for (int c = 1; c < 5; ++c) {
        mx.x = fmaxf(mx.x, v[c].x); mx.y = fmaxf(mx.y, v[c].y);
        mx.z = fmaxf(mx.z, v[c].z); mx.w = fmaxf(mx.w, v[c].w);
    }
    mx.x = fmaxf(mx.x, __shfl_xor(mx.x, 1));
    mx.y = fmaxf(mx.y, __shfl_xor(mx.y, 1));
    mx.z = fmaxf(mx.z, __shfl_xor(mx.z, 1));
    mx.w = fmaxf(mx.w, __shfl_xor(mx.w, 1));
    mx.x = fmaxf(mx.x, __shfl_xor(mx.x, 2));
    mx.y = fmaxf(mx.y, __shfl_xor(mx.y, 2));
    mx.z = fmaxf(mx.z, __shfl_xor(mx.z, 2));
    mx.w = fmaxf(mx.w, __shfl_xor(mx.w, 2));

    float ma = (q & 1) ? ((q & 2) ? mx.w : mx.y) : ((q & 2) ? mx.z : mx.x);
    float ca = (q & 1) ? ((q & 2) ? cv.w : cv.y) : ((q & 2) ? cv.z : cv.x);
    u32 sb = __float_as_uint(sqrtf(__fmul_rn(sigm(ma), sigm(ca))));
    int n = mod * NMOD + nm + q;
    keyAll[(size_t)b * NTOT + n] = ((u64)sb << 16) | (u64)(65535 - n);
}

// ---------------- kernel 2: fused select (LDS hist + B1 + compact + rank-sort) ----------------
__global__ __launch_bounds__(1024)
void select_kernel(const u64* __restrict__ keyAll, u64* __restrict__ topkey,
                   u32* __restrict__ maxcG) {
    int b = blockIdx.x, tid = threadIdx.x;
    int lane = tid & 63, wid = tid >> 6;
    __shared__ u32 shist[NBIN];          // 64KB; reused as double sk[] after B1
    __shared__ u32 warep[16];
    __shared__ int sB1;
    __shared__ u32 scnt;
    double* sd = (double*)shist;

    if (tid == 0) { maxcG[b * 32] = 0u; scnt = 0u; }
    #pragma unroll
    for (int j = 0; j < NBIN / 1024; ++j) shist[tid + j * 1024] = 0u;
    __syncthreads();

    const u64* keys = keyAll + (size_t)b * NTOT;
    const u64 SENT = ~0ull;
    for (int n0 = 0; n0 < NTOT; n0 += 8192) {
        u64 kk[8];
        #pragma unroll
        for (int r = 0; r < 8; ++r) {
            int idx = n0 + r * 1024 + tid;
            kk[r] = (idx < NTOT) ? keys[idx] : SENT;
        }
        #pragma unroll
        for (int r = 0; r < 8; ++r)
            if (kk[r] != SENT) atomicAdd(&shist[(u32)(kk[r] >> 32)], 1u);
    }
    __syncthreads();

    u32 loc[16]; u32 sum = 0;
    #pragma unroll
    for (int j = 0; j < 16; ++j) { loc[j] = shist[NBIN - 1 - (tid * 16 + j)]; sum += loc[j]; }
    u32 v = sum;
    #pragma unroll
    for (int off = 1; off < 64; off <<= 1) {
        u32 t2 = (u32)__shfl_up((int)v, off);
        if (lane >= off) v += t2;
    }
    if (lane == 63) warep[wid] = v;
    __syncthreads();
    if (tid < 16) {
        u32 p = warep[tid];
        #pragma unroll
        for (int off = 1; off < 16; off <<= 1) {
            u32 t2 = (u32)__shfl_up((int)p, off);
            if (tid >= off) p += t2;
        }
        warep[tid] = p;
    }
    __syncthreads();
    u32 incl = v + (wid ? warep[wid - 1] : 0u);
    u32 excl = incl - sum;
    if (excl < (u32)MAXD && incl >= (u32)MAXD) {
        u32 c = excl;
        #pragma unroll
        for (int j = 0; j < 16; ++j) {
            c += loc[j];
            if (c >= (u32)MAXD) { sB1 = NBIN - 1 - (tid * 16 + j); break; }
        }
    }
    __syncthreads();
    int B1 = sB1;

    for (int n0 = 0; n0 < NTOT; n0 += 8192) {
        u64 kk[8];
        #pragma unroll
        for (int r = 0; r < 8; ++r) {
            int idx = n0 + r * 1024 + tid;
            kk[r] = (idx < NTOT) ? keys[idx] : 0ull;   // real keys never 0
        }
        #pragma unroll
        for (int r = 0; r < 8; ++r) {
            if (kk[r] != 0ull && (int)(kk[r] >> 32) >= B1) {
                u32 p = atomicAdd(&scnt, 1u);
                if (p < CANDCAP - 2) sd[p] = (double)kk[r];   // 48-bit keys exact
            }
        }
    }
    __syncthreads();
    int C = min((int)scnt, CANDCAP - 2);
    if (tid == 0) { sd[C] = -1.0; sd[C + 1] = -1.0; }
    __syncthreads();

    for (int i = tid; i < C; i += 1024) {
        double ki = sd[i];
        int rank = 0;
        const double2* sd2 = (const double2*)sd;
        int C2 = (C + 1) >> 1;
        for (int j = 0; j < C2; ++j) {
            double2 v2 = sd2[j];
            rank += (v2.x > ki) ? 1 : 0;
            rank += (v2.y > ki) ? 1 : 0;
        }
        if (rank < MAXD) topkey[(size_t)b * KPAD + rank] = (u64)ki;
    }
}

// ---------------- kernel 3: gather winners (pair-split channels) ----------------
__global__ __launch_bounds__(128)
void gather_kernel(Ptrs ptrs, const u64* __restrict__ topkey,
                   float4* __restrict__ traw, float* __restrict__ tscore,
                   float* __restrict__ tclsf, u32* __restrict__ validwords,
                   u32* __restrict__ maxcG) {
    #pragma clang fp contract(off)
    int b = blockIdx.y;
    int tid = threadIdx.x;
    int half = tid & 1;
    int i = blockIdx.x * 64 + (tid >> 1);
    int active = (i < MAXD);

    float score = 0.f;
    float best = -1.0f; int bi = 0;
    float ra = 0.f, rb2 = 0.f;
    int pos = 0, w = 1, s = 0;
    if (active) {
        u64 key = topkey[(size_t)b * KPAD + i];
        int n = 65535 - (int)(key & 0xFFFFull);
        score = __uint_as_float((u32)(key >> 16));
        int mod = (n >= NMOD) ? 1 : 0;
        int nm = n - mod * NMOD;
        int l, hw;
        level_of(nm, l, pos, w, s, hw);
        const float* clsP = ptrs.p[mod * 15 + l];
        const float* regP = ptrs.p[mod * 15 + 10 + l];
        const float* cbp = clsP + (size_t)b * 20 * hw + pos;
        const float* rbp = regP + (size_t)b * 4 * hw + pos;
        float cl[10];
        int c0 = half * 10;
        #pragma unroll
        for (int c = 0; c < 10; ++c) cl[c] = cbp[(size_t)(c0 + c) * hw];
        ra  = rbp[(size_t)(half * 2) * hw];
        rb2 = rbp[(size_t)(half * 2 + 1) * hw];
        #pragma unroll
        for (int c = 0; c < 10; ++c) {
            float p = sigm(cl[c]);
            if (p > best) { best = p; bi = c0 + c; }
        }
    }
    float po  = __shfl_xor(best, 1);
    int   bio = __shfl_xor(bi, 1);
    float rao = __shfl_xor(ra, 1);
    float rbo = __shfl_xor(rb2, 1);
    if (half == 0) { if (po > best)  { best = po; bi = bio; } }
    else           { if (po >= best) { best = po; bi = bio; } }
    float clsf = active ? (float)(bi + 1) : 0.f;
    float r0 = half ? rao : ra,  r1 = half ? rbo : rb2;
    float r2 = half ? ra  : rao, r3 = half ? rb2 : rbo;

    float4 bx = make_float4(0.f, 0.f, 0.f, 0.f);
    if (active) {
        int xi = pos % w, yi = pos / w;
        float cx = (float)(xi * s + (s >> 1));
        float cy = (float)(yi * s + (s >> 1));
        bx.x = cx - r0; bx.y = cy - r1; bx.z = cx + r2; bx.w = cy + r3;
    }
    int valid = active && (score >= 0.05f) && (half == 0);
    float contrib = valid ? fmaxf(0.0f, fmaxf(fmaxf(bx.x, bx.y), fmaxf(bx.z, bx.w))) : 0.0f;
    float red = contrib;
    #pragma unroll
    for (int off = 32; off > 0; off >>= 1) red = fmaxf(red, __shfl_down(red, off));
    if ((tid & 63) == 0) atomicMax(&maxcG[b * 32], __float_as_uint(red));
    u64 ball = __ballot(valid != 0);
    if ((tid & 63) == 0) {
        u32 word = 0;
        for (int j = 0; j < 32; ++j) word |= (u32)((ball >> (2 * j)) & 1ull) << j;
        validwords[b * 32 + blockIdx.x * 2 + (tid >> 6)] = word;
    }
    if (half == 0) {
        size_t oo = (size_t)b * KPAD + i;
        traw[oo] = bx; tscore[oo] = score; tclsf[oo] = clsf;   // zeros for i >= MAXD
    }
}

// ---------------- kernel 4: IoU>0.6 bitmask, upper-triangle units ----------------
#define SW(t) ((((t) & 31) << 3) | ((t) >> 5))
__global__ __launch_bounds__(64)
void mask_kernel(const float4* __restrict__ traw, const float* __restrict__ tclsf,
                 const u32* __restrict__ maxcG, u32* __restrict__ maskG) {
    #pragma clang fp contract(off)
    int u = blockIdx.x, b = blockIdx.y, tid = threadIdx.x;
    int g, wg;
    if (u < 128)      { g = u >> 2;                 wg = u & 3; }
    else if (u < 224) { int i2 = u - 128; g = 32 + i2 / 3;      wg = 1 + i2 % 3; }
    else if (u < 288) { int i2 = u - 224; g = 64 + (i2 >> 1);   wg = 2 + (i2 & 1); }
    else              { g = 96 + (u - 288);         wg = 3; }
    int i0 = g * 8, j0 = wg * 256;
    float m1 = __uint_as_float(maxcG[b * 32]) + 1.0f;

    __shared__ float cx1[256], cy1[256], cx2[256], cy2[256], ca[256];
    for (int t = tid; t < 256; t += 64) {
        float4 f = traw[(size_t)b * KPAD + j0 + t];
        float o = __fmul_rn(tclsf[(size_t)b * KPAD + j0 + t], m1);
        float ox1 = __fadd_rn(f.x, o), oy1 = __fadd_rn(f.y, o);
        float ox2 = __fadd_rn(f.z, o), oy2 = __fadd_rn(f.w, o);
        float dw = ox2 - ox1 + 1.0f;
        float dh = oy2 - oy1 + 1.0f;
        int ts = SW(t);
        cx1[ts] = ox1; cy1[ts] = oy1; cx2[ts] = ox2; cy2[ts] = oy2;
        ca[ts] = __fmul_rn(dw, dh);
    }
    __syncthreads();

    int ir = tid >> 3, wr = tid & 7;
    int i = i0 + ir;
    float4 fi = traw[(size_t)b * KPAD + i];
    float oi = __fmul_rn(tclsf[(size_t)b * KPAD + i], m1);
    float ix1 = __fadd_rn(fi.x, oi), iy1 = __fadd_rn(fi.y, oi);
    float ix2 = __fadd_rn(fi.z, oi), iy2 = __fadd_rn(fi.w, oi);
    float dwi = ix2 - ix1 + 1.0f, dhi = iy2 - iy1 + 1.0f;
    float ai = __fmul_rn(dwi, dhi);
    u32 bits = 0;
    int jb = wr * 32;
    for (int jj = 0; jj < 32; ++jj) {
        int js = SW(jb + jj);
        float iw = fminf(ix2, cx2[js]) - fmaxf(ix1, cx1[js]) + 1.0f;
        iw = fmaxf(iw, 0.0f);
        float ih = fminf(iy2, cy2[js]) - fmaxf(iy1, cy1[js]) + 1.0f;
        ih = fmaxf(ih, 0.0f);
        float inter = iw * ih;
        float denom = (ai + ca[js]) - inter;
        float iou = inter / denom;
        bits |= (iou > 0.6f) ? (1u << jj) : 0u;
    }
    maskG[((size_t)b * KPAD + i) * 32 + wg * 8 + wr] = bits;
}

// ---------------- kernel 5: scan_out v2 — stage mask to LDS, then 1-wave scan ----------------
__global__ __launch_bounds__(512)
void scan_out_kernel(const u32* __restrict__ maskG, const u32* __restrict__ validbits,
                     const float4* __restrict__ traw, const float* __restrict__ tscore,
                     const float* __restrict__ tclsf, float* __restrict__ out) {
    __shared__ u32 sm[KPAD * 32];   // 128KB mask copy
    __shared__ u32 keeps[32];
    int b = blockIdx.x, tid = threadIdx.x;

    // phase 1: 8 waves stage 128KB (16 x dwordx4 per thread)
    const uint4* s4 = (const uint4*)(maskG + (size_t)b * KPAD * 32);
    uint4* d4 = (uint4*)sm;
    #pragma unroll
    for (int r = 0; r < 16; ++r) d4[tid + r * 512] = s4[tid + r * 512];
    __syncthreads();

    // phase 2: wave 0 sequential greedy scan from LDS (ring-16 prefetch)
    if (tid < 64) {
        int lane = tid, lw = lane & 31;
        u32 vreg = (lane < 32) ? validbits[b * 32 + lane] : 0u;
        u32 removed = 0u, keepw = 0u;
        u32 mA[8], mB[8];
        #pragma unroll
        for (int d = 0; d < 8; ++d) {
            mA[d] = sm[d * 32 + lw];
            mB[d] = sm[(d + 8) * 32 + lw];
        }
        auto step8 = [&](int base, u32* ms) {
            #pragma unroll
            for (int d = 0; d < 8; ++d) {
                int i = base + d;
                int wi = i >> 5, bi2 = i & 31;
                u32 rw = (u32)__builtin_amdgcn_readlane((int)removed, wi);
                u32 vw = (u32)__builtin_amdgcn_readlane((int)vreg, wi);
                u32 k = ((vw >> bi2) & 1u) & (~(rw >> bi2) & 1u);
                if (k) removed |= ms[d];
                if (lane == wi) keepw |= (k << bi2);
                ms[d] = sm[(i + 16) * 32 + lw];   // rows <= 1015 < 1024 staged
            }
        };
        for (int t = 0; t < 62; ++t) { step8(t * 16, mA); step8(t * 16 + 8, mB); }
        step8(992, mA);
        if (lane < 32) keeps[lane] = keepw;
    }
    __syncthreads();

    // phase 3: outputs with all 512 threads
    const int BQ = BATCH * MAXD;
    for (int s2 = tid; s2 < MAXD; s2 += 512) {
        u32 kf = (keeps[s2 >> 5] >> (s2 & 31)) & 1u;
        size_t oo = (size_t)b * KPAD + s2;
        float score = tscore[oo];
        float clsf = tclsf[oo];
        float4 bx = traw[oo];
        float x1 = fminf(fmaxf(bx.x, 0.f), 1279.f);
        float y1 = fminf(fmaxf(bx.y, 0.f), 1023.f);
        float x2 = fminf(fmaxf(bx.z, 0.f), 1279.f);
        float y2 = fminf(fmaxf(bx.w, 0.f), 1023.f);
        int base = b * MAXD + s2;
        out[base] = kf ? score : 0.0f;
        out[BQ + base] = kf ? clsf : 0.0f;
        float* ob = out + 2 * BQ + (size_t)base * 4;
        ob[0] = kf ? x1 : 0.f; ob[1] = kf ? y1 : 0.f;
        ob[2] = kf ? x2 : 0.f; ob[3] = kf ? y2 : 0.f;
        out[6 * BQ + base] = kf ? 1.0f : 0.0f;
    }
}

// ---------------- launch (6 nodes, no memsets) ----------------
extern "C" void kernel_launch(void* const* d_in, const int* in_sizes, int n_in,
                              void* d_out, int out_size, void* d_ws, size_t ws_size,
                              hipStream_t stream) {
    Ptrs ptrs;
    for (int i = 0; i < 30; ++i) ptrs.p[i] = (const float*)d_in[i];

    char* ws = (char*)d_ws;
    u64*    keyAll    = (u64*)   (ws + OFF_KEY);
    u64*    topkey    = (u64*)   (ws + OFF_TOPK);
    float4* traw      = (float4*)(ws + OFF_TRAW);
    float*  tscore    = (float*) (ws + OFF_TSCORE);
    float*  tclsf     = (float*) (ws + OFF_TCLSF);
    u32*    maxcG     = (u32*)   (ws + OFF_MAXC);
    u32*    validbits = (u32*)   (ws + OFF_VALID);
    u32*    maskG     = (u32*)   (ws + OFF_MASK);
    float*  out       = (float*)d_out;

    decode_lds_kernel<<<dim3(50, BATCH), 256, 0, stream>>>(ptrs, keyAll);
    decode_tail_kernel<<<dim3(14, BATCH), 256, 0, stream>>>(ptrs, keyAll);
    select_kernel<<<BATCH, 1024, 0, stream>>>(keyAll, topkey, maxcG);
    gather_kernel<<<dim3(16, BATCH), 128, 0, stream>>>(ptrs, topkey, traw, tscore, tclsf,
                                                       validbits, maxcG);
    mask_kernel<<<dim3(320, BATCH), 64, 0, stream>>>(traw, tclsf, maxcG, maskG);
    scan_out_kernel<<<BATCH, 512, 0, stream>>>(maskG, validbits, traw, tscore, tclsf, out);
}